// Round 8
// baseline (1976.831 us; speedup 1.0000x reference)
//
#include <hip/hip_runtime.h>

typedef unsigned short u16;
typedef unsigned int u32;
typedef float f32x4 __attribute__((ext_vector_type(4)));
typedef __bf16 bf16x8 __attribute__((ext_vector_type(8)));
typedef u16 u16x4 __attribute__((ext_vector_type(4)));

// B=256, T=512, FIN=128, H=256, 3H=768
#define TB 256
#define TT 512
#define TC 128  // T-chunk for the gemm2->gru pipeline

__device__ __forceinline__ u16 f2b(float f) {
  u32 x = __float_as_uint(f);
  return (u16)((x + 0x7fffu + ((x >> 16) & 1u)) >> 16);
}
__device__ __forceinline__ float blo(u32 u) { return __uint_as_float(u << 16); }
__device__ __forceinline__ float bhi(u32 u) { return __uint_as_float(u & 0xffff0000u); }

// ---------------- casts ----------------
__global__ void cast4_kernel(const float* __restrict__ in, u16* __restrict__ out, int n4) {
  int i = blockIdx.x * blockDim.x + threadIdx.x;
  for (; i < n4; i += gridDim.x * blockDim.x) {
    f32x4 v = ((const f32x4*)in)[i];
    u16x4 o = { f2b(v[0]), f2b(v[1]), f2b(v[2]), f2b(v[3]) };
    ((u16x4*)out)[i] = o;
  }
}

// in: (K,N) fp32 row-major -> out: (N,K) bf16 row-major (i.e. B^T for GEMM)
__global__ void tcast_kernel(const float* __restrict__ in, u16* __restrict__ out, int K, int N) {
  int idx = blockIdx.x * blockDim.x + threadIdx.x;
  if (idx < K * N) {
    int k = idx / N, n = idx % N;
    out[n * K + k] = f2b(in[idx]);
  }
}

// ---------------- GEMM: C = A @ B + bias, A bf16 row-major, Bt = B^T bf16 (N,K) ----------------
// 128x128 tile, BK=32, 4 waves each owning a 64x64 quadrant, mfma_f32_16x16x32_bf16.
// MODE 0: A rows = bm*128+r (dense), relu, C row-major ldc=256 (h1).
// MODE 1: A rows = bm*512 + t0 + r (T-chunk of batch bm), no relu, C[(bm*128+r)*768+n] (xg chunk).
template<int KT, int MODE>
__global__ __launch_bounds__(256) void gemm_bf16(const u16* __restrict__ A, const u16* __restrict__ Bt,
                                                 const float* __restrict__ bias, u16* __restrict__ C,
                                                 int t0) {
  constexpr int K = KT * 32;
  __shared__ u16 As[128 * 40];  // pad 32->40 shorts/row: conflict-free b128 frag reads
  __shared__ u16 Bs[128 * 40];
  const int tid = threadIdx.x;
  const int bm = blockIdx.x, bn = blockIdx.y;
  const int lane = tid & 63, wid = tid >> 6;
  const int l15 = lane & 15, l4 = lane >> 4;
  const int qm = (wid >> 1) * 64, qn = (wid & 1) * 64;

  const int c0 = tid, c1 = tid + 256;  // 16B chunks: chunk c covers LDS row c/4, k-elems (c%4)*8..+8
  const int ar0 = (MODE == 0) ? (bm * 128 + (c0 >> 2)) : (bm * 512 + t0 + (c0 >> 2));
  const int ar1 = (MODE == 0) ? (bm * 128 + (c1 >> 2)) : (bm * 512 + t0 + (c1 >> 2));
  const size_t ga0 = (size_t)ar0 * K + (c0 & 3) * 8;
  const size_t ga1 = (size_t)ar1 * K + (c1 & 3) * 8;
  const size_t gb0 = (size_t)(bn * 128 + (c0 >> 2)) * K + (c0 & 3) * 8;
  const size_t gb1 = (size_t)(bn * 128 + (c1 >> 2)) * K + (c1 & 3) * 8;
  const int sa0 = (c0 >> 2) * 40 + (c0 & 3) * 8;
  const int sa1 = (c1 >> 2) * 40 + (c1 & 3) * 8;

  uint4 ra0 = *(const uint4*)(A + ga0);
  uint4 ra1 = *(const uint4*)(A + ga1);
  uint4 rb0 = *(const uint4*)(Bt + gb0);
  uint4 rb1 = *(const uint4*)(Bt + gb1);

  f32x4 acc[4][4] = {};

  for (int kt = 0; kt < KT; ++kt) {
    __syncthreads();
    *(uint4*)(As + sa0) = ra0;
    *(uint4*)(As + sa1) = ra1;
    *(uint4*)(Bs + sa0) = rb0;
    *(uint4*)(Bs + sa1) = rb1;
    __syncthreads();
    if (kt + 1 < KT) {  // prefetch next tile into regs under the MFMA phase
      const int ko = (kt + 1) * 32;
      ra0 = *(const uint4*)(A + ga0 + ko);
      ra1 = *(const uint4*)(A + ga1 + ko);
      rb0 = *(const uint4*)(Bt + gb0 + ko);
      rb1 = *(const uint4*)(Bt + gb1 + ko);
    }
    bf16x8 af[4], bfr[4];
#pragma unroll
    for (int mt = 0; mt < 4; ++mt)
      af[mt] = *(const bf16x8*)(As + (qm + mt * 16 + l15) * 40 + l4 * 8);
#pragma unroll
    for (int nt = 0; nt < 4; ++nt)
      bfr[nt] = *(const bf16x8*)(Bs + (qn + nt * 16 + l15) * 40 + l4 * 8);
#pragma unroll
    for (int mt = 0; mt < 4; ++mt)
#pragma unroll
      for (int nt = 0; nt < 4; ++nt)
        acc[mt][nt] = __builtin_amdgcn_mfma_f32_16x16x32_bf16(af[mt], bfr[nt], acc[mt][nt], 0, 0, 0);
  }

#pragma unroll
  for (int mt = 0; mt < 4; ++mt) {
#pragma unroll
    for (int nt = 0; nt < 4; ++nt) {
      const int n = bn * 128 + qn + nt * 16 + l15;
      const float bv = bias[n];
#pragma unroll
      for (int j = 0; j < 4; ++j) {
        const int rloc = qm + mt * 16 + l4 * 4 + j;  // D: row=(lane>>4)*4+j, col=lane&15
        float v = acc[mt][nt][j] + bv;
        if (MODE == 0) {
          v = fmaxf(v, 0.f);
          C[(size_t)(bm * 128 + rloc) * 256 + n] = f2b(v);
        } else {
          C[((size_t)bm * 128 + rloc) * 768 + n] = f2b(v);
        }
      }
    }
  }
}

// ---------------- GRU chunk: 16 WGs x 512 threads; WG g owns batch rows 16g..16g+15. ----------------
// Processes TC steps; hidden state carried in global hstate (256x256 f32).
// Full Wr (bf16, as B-fragments) register-resident: wave w holds cols [96w,96w+96) = 48 frags.
// xg chunk layout: (b, t_local, 768) -> per-batch t-sequential streaming.
// ONLY change vs the R3-passing kernel: xq loads are prefetched one full step ahead
// (register double-buffer) so the ~900-cyc HBM/L2 latency hides under the MFMA+gate phases.
__global__ __launch_bounds__(512) void gru_kernel(const u16* __restrict__ xgc, const u16* __restrict__ WrT,
                                                  const float* __restrict__ br, float* __restrict__ hstate,
                                                  int t0) {
  __shared__ float h_f[16 * 264];   // fp32 master h, pad 256->264
  __shared__ u16 h_b[16 * 264];     // bf16 copy (MFMA A-tile)
  __shared__ float recs[16 * 768];  // rec = h @ Wr exchange
  __shared__ float brs[768];
  const int tid = threadIdx.x;
  const int g = blockIdx.x;
  const int lane = tid & 63, wid = tid >> 6;
  const int l15 = lane & 15, l4 = lane >> 4;

  bf16x8 bw[8][6];
#pragma unroll
  for (int kk = 0; kk < 8; ++kk)
#pragma unroll
    for (int nt = 0; nt < 6; ++nt) {
      const int col = wid * 96 + nt * 16 + l15;
      bw[kk][nt] = *(const bf16x8*)(WrT + (size_t)col * 256 + kk * 32 + l4 * 8);
    }

  const int b = tid >> 5;          // local batch row 0..15
  const int c0 = (tid & 31) * 8;   // h-cols c0..c0+7

  if (t0 == 0) {
    for (int i = tid; i < 16 * 264; i += 512) { h_f[i] = 0.f; h_b[i] = 0; }
  } else {
    // restore carried state (every thread owns rows/cols disjointly: 16 rows x 32 col-groups)
    const float* hp = hstate + ((size_t)g * 16 + b) * 256 + c0;
    f32x4 v0 = *(const f32x4*)(hp);
    f32x4 v1 = *(const f32x4*)(hp + 4);
    *(f32x4*)(h_f + b * 264 + c0) = v0;
    *(f32x4*)(h_f + b * 264 + c0 + 4) = v1;
    u32 pk0 = (u32)f2b(v0[0]) | ((u32)f2b(v0[1]) << 16);
    u32 pk1 = (u32)f2b(v0[2]) | ((u32)f2b(v0[3]) << 16);
    u32 pk2 = (u32)f2b(v1[0]) | ((u32)f2b(v1[1]) << 16);
    u32 pk3 = (u32)f2b(v1[2]) | ((u32)f2b(v1[3]) << 16);
    *(uint4*)(h_b + b * 264 + c0) = make_uint4(pk0, pk1, pk2, pk3);
  }
  for (int i = tid; i < 768; i += 512) brs[i] = br[i];
  __syncthreads();

  // per-lane xg base (c0 folded in); step t lives at +t*768
  const u16* xb0 = xgc + (size_t)(g * 16 + b) * TC * 768 + c0;
  uint4 xzu = *(const uint4*)(xb0);
  uint4 xru = *(const uint4*)(xb0 + 256);
  uint4 xhu = *(const uint4*)(xb0 + 512);

  for (int tl = 0; tl < TC; ++tl) {
    // prefetch NEXT step's input-side gates (clamped on last step; value unused)
    const int tn = (tl + 1 < TC) ? (tl + 1) : tl;
    const u16* xn = xb0 + (size_t)tn * 768;
    const uint4 xzn = *(const uint4*)(xn);
    const uint4 xrn = *(const uint4*)(xn + 256);
    const uint4 xhn = *(const uint4*)(xn + 512);

    // rec = h @ Wr (wave's 96-col slice), M=16 = WG's batch rows
    f32x4 acc[6] = {};
#pragma unroll
    for (int kk = 0; kk < 8; ++kk) {
      const bf16x8 a = *(const bf16x8*)(h_b + l15 * 264 + kk * 32 + l4 * 8);
#pragma unroll
      for (int nt = 0; nt < 6; ++nt)
        acc[nt] = __builtin_amdgcn_mfma_f32_16x16x32_bf16(a, bw[kk][nt], acc[nt], 0, 0, 0);
    }
#pragma unroll
    for (int nt = 0; nt < 6; ++nt) {
      const int col = wid * 96 + nt * 16 + l15;
#pragma unroll
      for (int j = 0; j < 4; ++j)
        recs[(l4 * 4 + j) * 768 + col] = acc[nt][j];
    }
    __syncthreads();

    // gates: z=sig(xz+rz), r=sig(xr+rr), hh=relu(xh+r*rh), h=z*h+(1-z)*hh
    u32 pk[4];
#pragma unroll
    for (int half = 0; half < 2; ++half) {
      const int cc = c0 + 4 * half;
      f32x4 rz = *(const f32x4*)(recs + b * 768 + cc);
      f32x4 rr = *(const f32x4*)(recs + b * 768 + 256 + cc);
      f32x4 rh = *(const f32x4*)(recs + b * 768 + 512 + cc);
      rz += *(const f32x4*)(brs + cc);
      rr += *(const f32x4*)(brs + 256 + cc);
      rh += *(const f32x4*)(brs + 512 + cc);
      const u32 z0 = half ? xzu.z : xzu.x, z1 = half ? xzu.w : xzu.y;
      const u32 r0 = half ? xru.z : xru.x, r1 = half ? xru.w : xru.y;
      const u32 h0 = half ? xhu.z : xhu.x, h1 = half ? xhu.w : xhu.y;
      const f32x4 xzv = { blo(z0), bhi(z0), blo(z1), bhi(z1) };
      const f32x4 xrv = { blo(r0), bhi(r0), blo(r1), bhi(r1) };
      const f32x4 xhv = { blo(h0), bhi(h0), blo(h1), bhi(h1) };
      const f32x4 hov = *(const f32x4*)(h_f + b * 264 + cc);
      f32x4 hnv;
#pragma unroll
      for (int q = 0; q < 4; ++q) {
        const float z = 1.f / (1.f + __expf(-(xzv[q] + rz[q])));
        const float r = 1.f / (1.f + __expf(-(xrv[q] + rr[q])));
        const float hh = fmaxf(xhv[q] + r * rh[q], 0.f);
        hnv[q] = z * hov[q] + (1.f - z) * hh;
      }
      *(f32x4*)(h_f + b * 264 + cc) = hnv;
      pk[2 * half + 0] = (u32)f2b(hnv[0]) | ((u32)f2b(hnv[1]) << 16);
      pk[2 * half + 1] = (u32)f2b(hnv[2]) | ((u32)f2b(hnv[3]) << 16);
      if (tl == TC - 1)  // persist carried state for the next chunk
        *(f32x4*)(hstate + ((size_t)g * 16 + b) * 256 + cc) = hnv;
    }
    *(uint4*)(h_b + b * 264 + c0) = make_uint4(pk[0], pk[1], pk[2], pk[3]);
    __syncthreads();

    xzu = xzn; xru = xrn; xhu = xhn;
  }
}

// ---------------- output: y = [h,h] @ W2 + b2 = h @ (W2_top + W2_bot) + b2 ----------------
__global__ void out_kernel(const float* __restrict__ h, const float* __restrict__ W2,
                           const float* __restrict__ b2, float* __restrict__ y) {
  const int bb = blockIdx.x, j = threadIdx.x;  // 256 blocks x 128 threads
  const float* hr = h + (size_t)bb * 256;
  float s = b2[j];
  for (int i = 0; i < 256; ++i)
    s = fmaf(hr[i], W2[i * 128 + j] + W2[(i + 256) * 128 + j], s);
  y[(size_t)bb * 128 + j] = s;
}

extern "C" void kernel_launch(void* const* d_in, const int* in_sizes, int n_in,
                              void* d_out, int out_size, void* d_ws, size_t ws_size,
                              hipStream_t stream) {
  const float* x  = (const float*)d_in[0];
  const float* W1 = (const float*)d_in[1];
  const float* b1 = (const float*)d_in[2];
  const float* Wk = (const float*)d_in[3];
  const float* Wr = (const float*)d_in[4];
  const float* bi = (const float*)d_in[5];
  const float* br = (const float*)d_in[6];
  const float* W2 = (const float*)d_in[7];
  const float* b2 = (const float*)d_in[8];
  float* y = (float*)d_out;

  // workspace layout: 118,554,624 bytes total. x_bf overlays the chunk buffer
  // (dead before the first gemm2 chunk runs).
  const size_t NEED = 67108864ull + 50331648ull + 65536ull + 393216ull + 393216ull + 262144ull;
  if (ws_size < NEED) return;

  char* ws = (char*)d_ws;
  u16* h1    = (u16*)ws;  ws += 67108864;   // (131072,256) bf16
  u16* xgc   = (u16*)ws;  ws += 50331648;   // (256,128,768) bf16 chunk; xb overlay
  u16* W1T   = (u16*)ws;  ws += 65536;      // (256,128) bf16
  u16* WkT   = (u16*)ws;  ws += 393216;     // (768,256) bf16
  u16* WrT   = (u16*)ws;  ws += 393216;     // (768,256) bf16
  float* hstate = (float*)ws;               // (256,256) f32 carried GRU state
  u16* xb    = xgc;                         // (131072,128) bf16 overlay

  cast4_kernel<<<2048, 256, 0, stream>>>(x, xb, 16777216 / 4);
  tcast_kernel<<<128, 256, 0, stream>>>(W1, W1T, 128, 256);
  tcast_kernel<<<768, 256, 0, stream>>>(Wk, WkT, 256, 768);
  tcast_kernel<<<768, 256, 0, stream>>>(Wr, WrT, 256, 768);
  gemm_bf16<4, 0><<<dim3(1024, 2), 256, 0, stream>>>(xb, W1T, b1, h1, 0);
  for (int c = 0; c < TT / TC; ++c) {
    gemm_bf16<8, 1><<<dim3(256, 6), 256, 0, stream>>>(h1, WkT, bi, xgc, c * TC);
    gru_kernel<<<16, 512, 0, stream>>>(xgc, WrT, br, hstate, c * TC);
  }
  out_kernel<<<256, 128, 0, stream>>>(hstate, W2, b2, y);
}

// Round 9
// 1503.601 us; speedup vs baseline: 1.3147x; 1.3147x over previous
//
#include <hip/hip_runtime.h>

typedef unsigned short u16;
typedef unsigned int u32;
typedef float f32x4 __attribute__((ext_vector_type(4)));
typedef __bf16 bf16x8 __attribute__((ext_vector_type(8)));
typedef u16 u16x4 __attribute__((ext_vector_type(4)));

// B=256, T=512, FIN=128, H=256, 3H=768
#define TB 256
#define TT 512
#define TC 128  // T-chunk for the gemm2->gru pipeline

__device__ __forceinline__ u16 f2b(float f) {
  u32 x = __float_as_uint(f);
  return (u16)((x + 0x7fffu + ((x >> 16) & 1u)) >> 16);
}
__device__ __forceinline__ u32 pk2(float a, float b) {  // lo=bf16(a), hi=bf16(b)
  return (u32)f2b(a) | ((u32)f2b(b) << 16);
}
__device__ __forceinline__ float blo(u32 u) { return __uint_as_float(u << 16); }
__device__ __forceinline__ float bhi(u32 u) { return __uint_as_float(u & 0xffff0000u); }
__device__ __forceinline__ float sigm(float x) {
  return __builtin_amdgcn_rcpf(1.f + __expf(-x));
}

// ---------------- casts ----------------
__global__ void cast4_kernel(const float* __restrict__ in, u16* __restrict__ out, int n4) {
  int i = blockIdx.x * blockDim.x + threadIdx.x;
  for (; i < n4; i += gridDim.x * blockDim.x) {
    f32x4 v = ((const f32x4*)in)[i];
    u16x4 o = { f2b(v[0]), f2b(v[1]), f2b(v[2]), f2b(v[3]) };
    ((u16x4*)out)[i] = o;
  }
}

// in: (K,N) fp32 row-major -> out: (N,K) bf16 row-major (B^T for GEMM)
__global__ void tcast_kernel(const float* __restrict__ in, u16* __restrict__ out, int K, int N) {
  int idx = blockIdx.x * blockDim.x + threadIdx.x;
  if (idx < K * N) {
    int k = idx / N, n = idx % N;
    out[n * K + k] = f2b(in[idx]);
  }
}

// Wr (256,768) -> permuted B^T: pcol(w,nt,l15) holds original col n = gate*256 + 32w + 2*l15 + grp,
// nt = gate*2+grp. Wave w then owns gate triples (z,r,h) for h-cols {32w+2*l15+grp}.
__global__ void wrperm_kernel(const float* __restrict__ in, u16* __restrict__ out) {
  int idx = blockIdx.x * blockDim.x + threadIdx.x;
  if (idx < 256 * 768) {
    int k = idx / 768, n = idx % 768;
    int gate = n >> 8, c = n & 255;
    int w = c >> 5, cc = c & 31, l15 = cc >> 1, grp = cc & 1;
    int nt = gate * 2 + grp;
    out[((((w * 6 + nt) << 4) + l15) << 8) + k] = f2b(in[idx]);
  }
}

// biasMod = bi + [br_z, br_r, 0]: fold recurrent bias for z,r into the input-side GEMM
__global__ void biasmod_kernel(const float* __restrict__ bi, const float* __restrict__ br,
                               float* __restrict__ bm) {
  int n = blockIdx.x * blockDim.x + threadIdx.x;
  if (n < 768) bm[n] = bi[n] + (n < 512 ? br[n] : 0.f);
}

// ---------------- GEMM: C = A @ B + bias, A bf16 row-major, Bt = B^T bf16 (N,K) ----------------
// 128x128 tile, BK=32, 4 waves each owning a 64x64 quadrant, mfma_f32_16x16x32_bf16.
// MODE 0: A rows = bm*128+r (dense), relu, C row-major ldc=256 (h1).
// MODE 1: A rows = bm*512 + t0 + r (T-chunk of batch bm), no relu,
//         C rows = bm*128 + r, natural chunk layout (b, tl, n), ldc=768 (xg chunk).
template<int KT, int MODE>
__global__ __launch_bounds__(256) void gemm_bf16(const u16* __restrict__ A, const u16* __restrict__ Bt,
                                                 const float* __restrict__ bias, u16* __restrict__ C,
                                                 int t0) {
  constexpr int K = KT * 32;
  __shared__ u16 As[128 * 40];  // pad 32->40 shorts/row: conflict-free b128 frag reads
  __shared__ u16 Bs[128 * 40];
  const int tid = threadIdx.x;
  const int bm = blockIdx.x, bn = blockIdx.y;
  const int lane = tid & 63, wid = tid >> 6;
  const int l15 = lane & 15, l4 = lane >> 4;
  const int qm = (wid >> 1) * 64, qn = (wid & 1) * 64;

  const int c0 = tid, c1 = tid + 256;  // 16B chunks: chunk c covers LDS row c/4, k-elems (c%4)*8..+8
  const int ar0 = (MODE == 0) ? (bm * 128 + (c0 >> 2)) : (bm * 512 + t0 + (c0 >> 2));
  const int ar1 = (MODE == 0) ? (bm * 128 + (c1 >> 2)) : (bm * 512 + t0 + (c1 >> 2));
  const size_t ga0 = (size_t)ar0 * K + (c0 & 3) * 8;
  const size_t ga1 = (size_t)ar1 * K + (c1 & 3) * 8;
  const size_t gb0 = (size_t)(bn * 128 + (c0 >> 2)) * K + (c0 & 3) * 8;
  const size_t gb1 = (size_t)(bn * 128 + (c1 >> 2)) * K + (c1 & 3) * 8;
  const int sa0 = (c0 >> 2) * 40 + (c0 & 3) * 8;
  const int sa1 = (c1 >> 2) * 40 + (c1 & 3) * 8;

  uint4 ra0 = *(const uint4*)(A + ga0);
  uint4 ra1 = *(const uint4*)(A + ga1);
  uint4 rb0 = *(const uint4*)(Bt + gb0);
  uint4 rb1 = *(const uint4*)(Bt + gb1);

  f32x4 acc[4][4] = {};

  for (int kt = 0; kt < KT; ++kt) {
    __syncthreads();
    *(uint4*)(As + sa0) = ra0;
    *(uint4*)(As + sa1) = ra1;
    *(uint4*)(Bs + sa0) = rb0;
    *(uint4*)(Bs + sa1) = rb1;
    __syncthreads();
    if (kt + 1 < KT) {  // prefetch next tile into regs under the MFMA phase
      const int ko = (kt + 1) * 32;
      ra0 = *(const uint4*)(A + ga0 + ko);
      ra1 = *(const uint4*)(A + ga1 + ko);
      rb0 = *(const uint4*)(Bt + gb0 + ko);
      rb1 = *(const uint4*)(Bt + gb1 + ko);
    }
    bf16x8 af[4], bfr[4];
#pragma unroll
    for (int mt = 0; mt < 4; ++mt)
      af[mt] = *(const bf16x8*)(As + (qm + mt * 16 + l15) * 40 + l4 * 8);
#pragma unroll
    for (int nt = 0; nt < 4; ++nt)
      bfr[nt] = *(const bf16x8*)(Bs + (qn + nt * 16 + l15) * 40 + l4 * 8);
#pragma unroll
    for (int mt = 0; mt < 4; ++mt)
#pragma unroll
      for (int nt = 0; nt < 4; ++nt)
        acc[mt][nt] = __builtin_amdgcn_mfma_f32_16x16x32_bf16(af[mt], bfr[nt], acc[mt][nt], 0, 0, 0);
  }

#pragma unroll
  for (int mt = 0; mt < 4; ++mt) {
#pragma unroll
    for (int nt = 0; nt < 4; ++nt) {
      const int n = bn * 128 + qn + nt * 16 + l15;
      const float bv = bias[n];
#pragma unroll
      for (int j = 0; j < 4; ++j) {
        const int rloc = qm + mt * 16 + l4 * 4 + j;  // D: row=(lane>>4)*4+j, col=lane&15
        float v = acc[mt][nt][j] + bv;
        if (MODE == 0) {
          v = fmaxf(v, 0.f);
          C[(size_t)(bm * 128 + rloc) * 256 + n] = f2b(v);
        } else {
          C[((size_t)bm * 128 + rloc) * 768 + n] = f2b(v);
        }
      }
    }
  }
}

// ---------------- GRU chunk: 16 WGs x 512 threads (8 waves); WG g owns batch rows 16g..16g+15 ---
// Wave wid holds permuted Wr B-fragments for its 32 h-cols x 3 gates (192 regs, VGPR+AGPR).
// Gates computed in-register on the accumulator lanes; bf16 h ping-pongs through LDS;
// one barrier per step. xg is read from the NATURAL chunk layout (b, tl, n): per lane,
// 12 dword loads (4 batch rows x 3 gates, 2 h-cols each) -- 16 l15-lanes x 4B = coalesced
// 64-B lines. Loads issued at top of step, consumed after the MFMA phase (same-step hiding,
// the P3-proven pattern; one-step-ahead prefetch measured slower in R8).
__global__ __launch_bounds__(512, 2) void gru_kernel(const u16* __restrict__ xgc,
                                                     const u16* __restrict__ WrP,
                                                     const float* __restrict__ br,
                                                     float* __restrict__ hstate, int t0) {
  __shared__ u16 hb0[16 * 264];  // h bf16, [row][col], stride 264 (528 B) - ping
  __shared__ u16 hb1[16 * 264];  // pong
  const int tid = threadIdx.x, g = blockIdx.x;
  const int lane = tid & 63, wid = tid >> 6;
  const int l15 = lane & 15, l4 = lane >> 4;

  // register-resident Wr fragments: wave wid covers permuted cols [wid*96, wid*96+96)
  bf16x8 bw[8][6];
#pragma unroll
  for (int kk = 0; kk < 8; ++kk)
#pragma unroll
    for (int nt = 0; nt < 6; ++nt)
      bw[kk][nt] = *(const bf16x8*)(WrP + ((((wid * 6 + nt) << 4) + l15) << 8) + kk * 32 + l4 * 8);

  const int cbase = wid * 32 + l15 * 2;  // this lane's h-col pair
  const float brh0 = br[512 + cbase];
  const float brh1 = br[512 + cbase + 1];

  f32x4 h0v, h1v;  // fp32 master h for rows l4*4+j, cols cbase/cbase+1
  if (t0 == 0) {
    h0v = {0.f, 0.f, 0.f, 0.f};
    h1v = {0.f, 0.f, 0.f, 0.f};
  } else {
#pragma unroll
    for (int j = 0; j < 4; ++j) {
      float2 ld = *(const float2*)(hstate + ((size_t)g * 16 + l4 * 4 + j) * 256 + cbase);
      h0v[j] = ld.x; h1v[j] = ld.y;
    }
  }
#pragma unroll
  for (int j = 0; j < 4; ++j)
    *(u32*)(hb0 + (l4 * 4 + j) * 264 + cbase) = pk2(h0v[j], h1v[j]);
  __syncthreads();

  // natural xg: value (b_loc, tl, gate, col) at xgc[((g*16+b_loc)*TC + tl)*768 + gate*256 + col]
  const u16* xbj[4];
#pragma unroll
  for (int j = 0; j < 4; ++j)
    xbj[j] = xgc + (size_t)(g * 16 + l4 * 4 + j) * TC * 768 + cbase;

#define GRU_STEP(SRC, DST, TL)                                                              \
  {                                                                                         \
    u32 xzw[4], xrw[4], xhw[4];                                                             \
    _Pragma("unroll")                                                                       \
    for (int j = 0; j < 4; ++j) {                                                           \
      const u16* xq = xbj[j] + (size_t)(TL) * 768;                                          \
      xzw[j] = *(const u32*)(xq);                                                           \
      xrw[j] = *(const u32*)(xq + 256);                                                     \
      xhw[j] = *(const u32*)(xq + 512);                                                     \
    }                                                                                       \
    f32x4 acc[6] = {};                                                                      \
    _Pragma("unroll")                                                                       \
    for (int kk = 0; kk < 8; ++kk) {                                                        \
      const bf16x8 a = *(const bf16x8*)((SRC) + l15 * 264 + kk * 32 + l4 * 8);              \
      _Pragma("unroll")                                                                     \
      for (int nt = 0; nt < 6; ++nt)                                                        \
        acc[nt] = __builtin_amdgcn_mfma_f32_16x16x32_bf16(a, bw[kk][nt], acc[nt], 0, 0, 0); \
    }                                                                                       \
    _Pragma("unroll")                                                                       \
    for (int j = 0; j < 4; ++j) {                                                           \
      const float z0 = sigm(blo(xzw[j]) + acc[0][j]);                                       \
      const float z1 = sigm(bhi(xzw[j]) + acc[1][j]);                                       \
      const float r0 = sigm(blo(xrw[j]) + acc[2][j]);                                       \
      const float r1 = sigm(bhi(xrw[j]) + acc[3][j]);                                       \
      const float hh0 = fmaxf(fmaf(r0, acc[4][j] + brh0, blo(xhw[j])), 0.f);                \
      const float hh1 = fmaxf(fmaf(r1, acc[5][j] + brh1, bhi(xhw[j])), 0.f);                \
      h0v[j] = fmaf(z0, h0v[j] - hh0, hh0);                                                 \
      h1v[j] = fmaf(z1, h1v[j] - hh1, hh1);                                                 \
      *(u32*)((DST) + (l4 * 4 + j) * 264 + cbase) = pk2(h0v[j], h1v[j]);                    \
    }                                                                                       \
    __syncthreads();                                                                        \
  }

  for (int tl = 0; tl < TC; tl += 2) {
    GRU_STEP(hb0, hb1, tl);
    GRU_STEP(hb1, hb0, tl + 1);
  }
#undef GRU_STEP

  // persist carried state (lanes own disjoint (row, colpair) slots)
#pragma unroll
  for (int j = 0; j < 4; ++j) {
    float2 st = {h0v[j], h1v[j]};
    *(float2*)(hstate + ((size_t)g * 16 + l4 * 4 + j) * 256 + cbase) = st;
  }
}

// ---------------- output: y = [h,h] @ W2 + b2 = h @ (W2_top + W2_bot) + b2 ----------------
__global__ void out_kernel(const float* __restrict__ h, const float* __restrict__ W2,
                           const float* __restrict__ b2, float* __restrict__ y) {
  const int bb = blockIdx.x, j = threadIdx.x;  // 256 blocks x 128 threads
  const float* hr = h + (size_t)bb * 256;
  float s = b2[j];
  for (int i = 0; i < 256; ++i)
    s = fmaf(hr[i], W2[i * 128 + j] + W2[(i + 256) * 128 + j], s);
  y[(size_t)bb * 128 + j] = s;
}

extern "C" void kernel_launch(void* const* d_in, const int* in_sizes, int n_in,
                              void* d_out, int out_size, void* d_ws, size_t ws_size,
                              hipStream_t stream) {
  const float* x  = (const float*)d_in[0];
  const float* W1 = (const float*)d_in[1];
  const float* b1 = (const float*)d_in[2];
  const float* Wk = (const float*)d_in[3];
  const float* Wr = (const float*)d_in[4];
  const float* bi = (const float*)d_in[5];
  const float* br = (const float*)d_in[6];
  const float* W2 = (const float*)d_in[7];
  const float* b2 = (const float*)d_in[8];
  float* y = (float*)d_out;

  // workspace: 118.6 MB total; x_bf overlays the xg chunk buffer (dead before gemm2 runs)
  const size_t NEED = 67108864ull + 50331648ull + 65536ull + 393216ull + 393216ull + 262144ull + 4096ull;
  if (ws_size < NEED) return;

  char* ws = (char*)d_ws;
  u16* h1    = (u16*)ws;  ws += 67108864;   // (131072,256) bf16
  u16* xgc   = (u16*)ws;  ws += 50331648;   // (256,128,768) bf16 chunk, natural layout; xb overlay
  u16* W1T   = (u16*)ws;  ws += 65536;      // (256,128) bf16
  u16* WkT   = (u16*)ws;  ws += 393216;     // (768,256) bf16
  u16* WrP   = (u16*)ws;  ws += 393216;     // permuted Wr^T (768,256) bf16
  float* hstate = (float*)ws; ws += 262144; // (256,256) f32 carried GRU state
  float* biasM  = (float*)ws;               // 768 f32
  u16* xb    = xgc;                         // (131072,128) bf16 overlay

  cast4_kernel<<<2048, 256, 0, stream>>>(x, xb, 16777216 / 4);
  tcast_kernel<<<128, 256, 0, stream>>>(W1, W1T, 128, 256);
  tcast_kernel<<<768, 256, 0, stream>>>(Wk, WkT, 256, 768);
  wrperm_kernel<<<768, 256, 0, stream>>>(Wr, WrP);
  biasmod_kernel<<<3, 256, 0, stream>>>(bi, br, biasM);
  gemm_bf16<4, 0><<<dim3(1024, 2), 256, 0, stream>>>(xb, W1T, b1, h1, 0);
  for (int c = 0; c < TT / TC; ++c) {
    gemm_bf16<8, 1><<<dim3(256, 6), 256, 0, stream>>>(h1, WkT, biasM, xgc, c * TC);
    gru_kernel<<<16, 512, 0, stream>>>(xgc, WrP, br, hstate, c * TC);
  }
  out_kernel<<<256, 128, 0, stream>>>(hstate, W2, b2, y);
}

// Round 10
// 1058.570 us; speedup vs baseline: 1.8675x; 1.4204x over previous
//
#include <hip/hip_runtime.h>

typedef unsigned short u16;
typedef unsigned int u32;
typedef float f32x4 __attribute__((ext_vector_type(4)));
typedef __bf16 bf16x8 __attribute__((ext_vector_type(8)));
typedef u16 u16x4 __attribute__((ext_vector_type(4)));

// B=256, T=512, FIN=128, H=256, 3H=768
#define TB 256
#define TT 512
#define TC 128  // T-chunk for the gemm2->gru pipeline

__device__ __forceinline__ u16 f2b(float f) {
  u32 x = __float_as_uint(f);
  return (u16)((x + 0x7fffu + ((x >> 16) & 1u)) >> 16);
}
__device__ __forceinline__ u32 pk2(float a, float b) {  // lo=bf16(a), hi=bf16(b)
  return (u32)f2b(a) | ((u32)f2b(b) << 16);
}
__device__ __forceinline__ float blo(u32 u) { return __uint_as_float(u << 16); }
__device__ __forceinline__ float bhi(u32 u) { return __uint_as_float(u & 0xffff0000u); }
__device__ __forceinline__ float sigm(float x) {
  return __builtin_amdgcn_rcpf(1.f + __expf(-x));
}

// ---------------- casts ----------------
__global__ void cast4_kernel(const float* __restrict__ in, u16* __restrict__ out, int n4) {
  int i = blockIdx.x * blockDim.x + threadIdx.x;
  for (; i < n4; i += gridDim.x * blockDim.x) {
    f32x4 v = ((const f32x4*)in)[i];
    u16x4 o = { f2b(v[0]), f2b(v[1]), f2b(v[2]), f2b(v[3]) };
    ((u16x4*)out)[i] = o;
  }
}

// in: (K,N) fp32 row-major -> out: (N,K) bf16 row-major (B^T for GEMM)
__global__ void tcast_kernel(const float* __restrict__ in, u16* __restrict__ out, int K, int N) {
  int idx = blockIdx.x * blockDim.x + threadIdx.x;
  if (idx < K * N) {
    int k = idx / N, n = idx % N;
    out[n * K + k] = f2b(in[idx]);
  }
}

// Wr (256,768) -> permuted B^T: pcol(w,nt,l15) holds original col n = gate*256 + 32w + 2*l15 + grp,
// nt = gate*2+grp. Wave w then owns gate triples (z,r,h) for h-cols {32w+2*l15+grp}.
__global__ void wrperm_kernel(const float* __restrict__ in, u16* __restrict__ out) {
  int idx = blockIdx.x * blockDim.x + threadIdx.x;
  if (idx < 256 * 768) {
    int k = idx / 768, n = idx % 768;
    int gate = n >> 8, c = n & 255;
    int w = c >> 5, cc = c & 31, l15 = cc >> 1, grp = cc & 1;
    int nt = gate * 2 + grp;
    out[((((w * 6 + nt) << 4) + l15) << 8) + k] = f2b(in[idx]);
  }
}

// biasMod = bi + [br_z, br_r, 0]: fold recurrent bias for z,r into the input-side GEMM
__global__ void biasmod_kernel(const float* __restrict__ bi, const float* __restrict__ br,
                               float* __restrict__ bm) {
  int n = blockIdx.x * blockDim.x + threadIdx.x;
  if (n < 768) bm[n] = bi[n] + (n < 512 ? br[n] : 0.f);
}

// ---------------- GEMM: C = A @ B + bias, A bf16 row-major, Bt = B^T bf16 (N,K) ----------------
// 128x128 tile, BK=32, 4 waves each owning a 64x64 quadrant, mfma_f32_16x16x32_bf16.
// MODE 0: A rows = bm*128+r (dense), relu, C row-major ldc=256 (h1).
// MODE 1: A rows = bm*512 + t0 + r (T-chunk of batch bm), no relu,
//         C rows = bm*128 + r, natural chunk layout (b, tl, n), ldc=768 (xg chunk).
template<int KT, int MODE>
__global__ __launch_bounds__(256) void gemm_bf16(const u16* __restrict__ A, const u16* __restrict__ Bt,
                                                 const float* __restrict__ bias, u16* __restrict__ C,
                                                 int t0) {
  constexpr int K = KT * 32;
  __shared__ u16 As[128 * 40];  // pad 32->40 shorts/row: conflict-free b128 frag reads
  __shared__ u16 Bs[128 * 40];
  const int tid = threadIdx.x;
  const int bm = blockIdx.x, bn = blockIdx.y;
  const int lane = tid & 63, wid = tid >> 6;
  const int l15 = lane & 15, l4 = lane >> 4;
  const int qm = (wid >> 1) * 64, qn = (wid & 1) * 64;

  const int c0 = tid, c1 = tid + 256;  // 16B chunks: chunk c covers LDS row c/4, k-elems (c%4)*8..+8
  const int ar0 = (MODE == 0) ? (bm * 128 + (c0 >> 2)) : (bm * 512 + t0 + (c0 >> 2));
  const int ar1 = (MODE == 0) ? (bm * 128 + (c1 >> 2)) : (bm * 512 + t0 + (c1 >> 2));
  const size_t ga0 = (size_t)ar0 * K + (c0 & 3) * 8;
  const size_t ga1 = (size_t)ar1 * K + (c1 & 3) * 8;
  const size_t gb0 = (size_t)(bn * 128 + (c0 >> 2)) * K + (c0 & 3) * 8;
  const size_t gb1 = (size_t)(bn * 128 + (c1 >> 2)) * K + (c1 & 3) * 8;
  const int sa0 = (c0 >> 2) * 40 + (c0 & 3) * 8;
  const int sa1 = (c1 >> 2) * 40 + (c1 & 3) * 8;

  uint4 ra0 = *(const uint4*)(A + ga0);
  uint4 ra1 = *(const uint4*)(A + ga1);
  uint4 rb0 = *(const uint4*)(Bt + gb0);
  uint4 rb1 = *(const uint4*)(Bt + gb1);

  f32x4 acc[4][4] = {};

  for (int kt = 0; kt < KT; ++kt) {
    __syncthreads();
    *(uint4*)(As + sa0) = ra0;
    *(uint4*)(As + sa1) = ra1;
    *(uint4*)(Bs + sa0) = rb0;
    *(uint4*)(Bs + sa1) = rb1;
    __syncthreads();
    if (kt + 1 < KT) {  // prefetch next tile into regs under the MFMA phase
      const int ko = (kt + 1) * 32;
      ra0 = *(const uint4*)(A + ga0 + ko);
      ra1 = *(const uint4*)(A + ga1 + ko);
      rb0 = *(const uint4*)(Bt + gb0 + ko);
      rb1 = *(const uint4*)(Bt + gb1 + ko);
    }
    bf16x8 af[4], bfr[4];
#pragma unroll
    for (int mt = 0; mt < 4; ++mt)
      af[mt] = *(const bf16x8*)(As + (qm + mt * 16 + l15) * 40 + l4 * 8);
#pragma unroll
    for (int nt = 0; nt < 4; ++nt)
      bfr[nt] = *(const bf16x8*)(Bs + (qn + nt * 16 + l15) * 40 + l4 * 8);
#pragma unroll
    for (int mt = 0; mt < 4; ++mt)
#pragma unroll
      for (int nt = 0; nt < 4; ++nt)
        acc[mt][nt] = __builtin_amdgcn_mfma_f32_16x16x32_bf16(af[mt], bfr[nt], acc[mt][nt], 0, 0, 0);
  }

#pragma unroll
  for (int mt = 0; mt < 4; ++mt) {
#pragma unroll
    for (int nt = 0; nt < 4; ++nt) {
      const int n = bn * 128 + qn + nt * 16 + l15;
      const float bv = bias[n];
#pragma unroll
      for (int j = 0; j < 4; ++j) {
        const int rloc = qm + mt * 16 + l4 * 4 + j;  // D: row=(lane>>4)*4+j, col=lane&15
        float v = acc[mt][nt][j] + bv;
        if (MODE == 0) {
          v = fmaxf(v, 0.f);
          C[(size_t)(bm * 128 + rloc) * 256 + n] = f2b(v);
        } else {
          C[((size_t)bm * 128 + rloc) * 768 + n] = f2b(v);
        }
      }
    }
  }
}

// ---------------- GRU chunk: 16 WGs x 512 threads (8 waves); WG g owns batch rows 16g..16g+15 ---
// Wave wid holds permuted Wr B-fragments for its 32 h-cols x 3 gates (192 regs, VGPR+AGPR).
// Gates computed in-register on the accumulator lanes; bf16 h ping-pongs through LDS;
// one barrier per step. R10 delta vs R9: xq is staged through LDS with a one-step-ahead
// double buffer. Each thread loads 48 B of the WG's 16 natural-layout rows for step t+1
// (3 coalesced dwordx4: 32 threads/row x 16 B), ds_writes into xs[(t+1)&1]; the gate phase
// reads its 12 u32 from xs[t&1]. Global-load latency gets a full step (~2600 cyc) of cover.
// Row stride 776 u16 = 1552 B (16-B aligned rows; 97*16).
__global__ __launch_bounds__(512, 2) void gru_kernel(const u16* __restrict__ xgc,
                                                     const u16* __restrict__ WrP,
                                                     const float* __restrict__ br,
                                                     float* __restrict__ hstate, int t0) {
  __shared__ u16 hb0[16 * 264];  // h bf16, [row][col], stride 264 (528 B) - ping
  __shared__ u16 hb1[16 * 264];  // pong
  __shared__ u16 xs0[16 * 776];  // xq stage, [row][col 0..767], stride 776 - ping
  __shared__ u16 xs1[16 * 776];  // pong
  const int tid = threadIdx.x, g = blockIdx.x;
  const int lane = tid & 63, wid = tid >> 6;
  const int l15 = lane & 15, l4 = lane >> 4;

  // register-resident Wr fragments: wave wid covers permuted cols [wid*96, wid*96+96)
  bf16x8 bw[8][6];
#pragma unroll
  for (int kk = 0; kk < 8; ++kk)
#pragma unroll
    for (int nt = 0; nt < 6; ++nt)
      bw[kk][nt] = *(const bf16x8*)(WrP + ((((wid * 6 + nt) << 4) + l15) << 8) + kk * 32 + l4 * 8);

  const int cbase = wid * 32 + l15 * 2;  // this lane's h-col pair
  const float brh0 = br[512 + cbase];
  const float brh1 = br[512 + cbase + 1];

  // staging role: thread stages row rs, u16 cols {ksl, ksl+256, ksl+512} (+8 each)
  const int rs = tid >> 5, ksl = (tid & 31) * 8;
  const u16* xg_row = xgc + (size_t)(g * 16 + rs) * TC * 768 + ksl;
  u16* xw0 = xs0 + rs * 776 + ksl;
  u16* xw1 = xs1 + rs * 776 + ksl;

  f32x4 h0v, h1v;  // fp32 master h for rows l4*4+j, cols cbase/cbase+1
  if (t0 == 0) {
    h0v = {0.f, 0.f, 0.f, 0.f};
    h1v = {0.f, 0.f, 0.f, 0.f};
  } else {
#pragma unroll
    for (int j = 0; j < 4; ++j) {
      float2 ld = *(const float2*)(hstate + ((size_t)g * 16 + l4 * 4 + j) * 256 + cbase);
      h0v[j] = ld.x; h1v[j] = ld.y;
    }
  }
#pragma unroll
  for (int j = 0; j < 4; ++j)
    *(u32*)(hb0 + (l4 * 4 + j) * 264 + cbase) = pk2(h0v[j], h1v[j]);

  {  // pre-stage step 0 into xs0
    const uint4 s0 = *(const uint4*)(xg_row);
    const uint4 s1 = *(const uint4*)(xg_row + 256);
    const uint4 s2 = *(const uint4*)(xg_row + 512);
    *(uint4*)(xw0) = s0;
    *(uint4*)(xw0 + 256) = s1;
    *(uint4*)(xw0 + 512) = s2;
  }
  __syncthreads();

#define GRU_STEP(SRC, DST, XRD, XWR, TL)                                                    \
  {                                                                                         \
    /* issue next step's stage loads (clamped on last step; dead value) */                  \
    const int tn = ((TL) + 1 < TC) ? ((TL) + 1) : (TC - 1);                                 \
    const u16* xq = xg_row + (size_t)tn * 768;                                              \
    const uint4 s0 = *(const uint4*)(xq);                                                   \
    const uint4 s1 = *(const uint4*)(xq + 256);                                             \
    const uint4 s2 = *(const uint4*)(xq + 512);                                             \
    f32x4 acc[6] = {};                                                                      \
    _Pragma("unroll")                                                                       \
    for (int kk = 0; kk < 8; ++kk) {                                                        \
      const bf16x8 a = *(const bf16x8*)((SRC) + l15 * 264 + kk * 32 + l4 * 8);              \
      _Pragma("unroll")                                                                     \
      for (int nt = 0; nt < 6; ++nt)                                                        \
        acc[nt] = __builtin_amdgcn_mfma_f32_16x16x32_bf16(a, bw[kk][nt], acc[nt], 0, 0, 0); \
    }                                                                                       \
    /* stage next step's xq into the other buffer (read next step, after barrier) */        \
    *(uint4*)(XWR) = s0;                                                                    \
    *(uint4*)((XWR) + 256) = s1;                                                            \
    *(uint4*)((XWR) + 512) = s2;                                                            \
    _Pragma("unroll")                                                                       \
    for (int j = 0; j < 4; ++j) {                                                           \
      const u16* xr = (XRD) + (l4 * 4 + j) * 776 + cbase;                                   \
      const u32 xzw = *(const u32*)(xr);                                                    \
      const u32 xrw = *(const u32*)(xr + 256);                                              \
      const u32 xhw = *(const u32*)(xr + 512);                                              \
      const float z0 = sigm(blo(xzw) + acc[0][j]);                                          \
      const float z1 = sigm(bhi(xzw) + acc[1][j]);                                          \
      const float r0 = sigm(blo(xrw) + acc[2][j]);                                          \
      const float r1 = sigm(bhi(xrw) + acc[3][j]);                                          \
      const float hh0 = fmaxf(fmaf(r0, acc[4][j] + brh0, blo(xhw)), 0.f);                   \
      const float hh1 = fmaxf(fmaf(r1, acc[5][j] + brh1, bhi(xhw)), 0.f);                   \
      h0v[j] = fmaf(z0, h0v[j] - hh0, hh0);                                                 \
      h1v[j] = fmaf(z1, h1v[j] - hh1, hh1);                                                 \
      *(u32*)((DST) + (l4 * 4 + j) * 264 + cbase) = pk2(h0v[j], h1v[j]);                    \
    }                                                                                       \
    __syncthreads();                                                                        \
  }

  for (int tl = 0; tl < TC; tl += 2) {
    GRU_STEP(hb0, hb1, xs0, xw1, tl);      // compute step tl (data in xs0), stage tl+1 -> xs1
    GRU_STEP(hb1, hb0, xs1, xw0, tl + 1);  // compute step tl+1 (xs1), stage tl+2 -> xs0
  }
#undef GRU_STEP

  // persist carried state (lanes own disjoint (row, colpair) slots)
#pragma unroll
  for (int j = 0; j < 4; ++j) {
    float2 st = {h0v[j], h1v[j]};
    *(float2*)(hstate + ((size_t)g * 16 + l4 * 4 + j) * 256 + cbase) = st;
  }
}

// ---------------- output: y = [h,h] @ W2 + b2 = h @ (W2_top + W2_bot) + b2 ----------------
__global__ void out_kernel(const float* __restrict__ h, const float* __restrict__ W2,
                           const float* __restrict__ b2, float* __restrict__ y) {
  const int bb = blockIdx.x, j = threadIdx.x;  // 256 blocks x 128 threads
  const float* hr = h + (size_t)bb * 256;
  float s = b2[j];
  for (int i = 0; i < 256; ++i)
    s = fmaf(hr[i], W2[i * 128 + j] + W2[(i + 256) * 128 + j], s);
  y[(size_t)bb * 128 + j] = s;
}

extern "C" void kernel_launch(void* const* d_in, const int* in_sizes, int n_in,
                              void* d_out, int out_size, void* d_ws, size_t ws_size,
                              hipStream_t stream) {
  const float* x  = (const float*)d_in[0];
  const float* W1 = (const float*)d_in[1];
  const float* b1 = (const float*)d_in[2];
  const float* Wk = (const float*)d_in[3];
  const float* Wr = (const float*)d_in[4];
  const float* bi = (const float*)d_in[5];
  const float* br = (const float*)d_in[6];
  const float* W2 = (const float*)d_in[7];
  const float* b2 = (const float*)d_in[8];
  float* y = (float*)d_out;

  // workspace: 118.6 MB total; x_bf overlays the xg chunk buffer (dead before gemm2 runs)
  const size_t NEED = 67108864ull + 50331648ull + 65536ull + 393216ull + 393216ull + 262144ull + 4096ull;
  if (ws_size < NEED) return;

  char* ws = (char*)d_ws;
  u16* h1    = (u16*)ws;  ws += 67108864;   // (131072,256) bf16
  u16* xgc   = (u16*)ws;  ws += 50331648;   // (256,128,768) bf16 chunk, natural layout; xb overlay
  u16* W1T   = (u16*)ws;  ws += 65536;      // (256,128) bf16
  u16* WkT   = (u16*)ws;  ws += 393216;     // (768,256) bf16
  u16* WrP   = (u16*)ws;  ws += 393216;     // permuted Wr^T (768,256) bf16
  float* hstate = (float*)ws; ws += 262144; // (256,256) f32 carried GRU state
  float* biasM  = (float*)ws;               // 768 f32
  u16* xb    = xgc;                         // (131072,128) bf16 overlay

  cast4_kernel<<<2048, 256, 0, stream>>>(x, xb, 16777216 / 4);
  tcast_kernel<<<128, 256, 0, stream>>>(W1, W1T, 128, 256);
  tcast_kernel<<<768, 256, 0, stream>>>(Wk, WkT, 256, 768);
  wrperm_kernel<<<768, 256, 0, stream>>>(Wr, WrP);
  biasmod_kernel<<<3, 256, 0, stream>>>(bi, br, biasM);
  gemm_bf16<4, 0><<<dim3(1024, 2), 256, 0, stream>>>(xb, W1T, b1, h1, 0);
  for (int c = 0; c < TT / TC; ++c) {
    gemm_bf16<8, 1><<<dim3(256, 6), 256, 0, stream>>>(h1, WkT, biasM, xgc, c * TC);
    gru_kernel<<<16, 512, 0, stream>>>(xgc, WrP, br, hstate, c * TC);
  }
  out_kernel<<<256, 128, 0, stream>>>(hstate, W2, b2, y);
}

// Round 11
// 1040.937 us; speedup vs baseline: 1.8991x; 1.0169x over previous
//
#include <hip/hip_runtime.h>

typedef unsigned short u16;
typedef unsigned int u32;
typedef float f32x4 __attribute__((ext_vector_type(4)));
typedef __bf16 bf16x8 __attribute__((ext_vector_type(8)));
typedef u16 u16x4 __attribute__((ext_vector_type(4)));

// B=256, T=512, FIN=128, H=256, 3H=768
#define TB 256
#define TT 512
#define TC 128  // T-chunk for the gemm2->gru pipeline

__device__ __forceinline__ u16 f2b(float f) {
  u32 x = __float_as_uint(f);
  return (u16)((x + 0x7fffu + ((x >> 16) & 1u)) >> 16);
}
__device__ __forceinline__ u32 pk2(float a, float b) {  // lo=bf16(a), hi=bf16(b)
  return (u32)f2b(a) | ((u32)f2b(b) << 16);
}
__device__ __forceinline__ u32 pkbf(float a, float b) {  // RNE, bit-identical to pk2 (R4/R5 bisect)
  u32 r;
  asm("v_cvt_pk_bf16_f32 %0, %1, %2" : "=v"(r) : "v"(a), "v"(b));
  return r;
}
__device__ __forceinline__ float blo(u32 u) { return __uint_as_float(u << 16); }
__device__ __forceinline__ float bhi(u32 u) { return __uint_as_float(u & 0xffff0000u); }
__device__ __forceinline__ float sigm(float x) {
  return __builtin_amdgcn_rcpf(1.f + __expf(-x));
}

// ---------------- casts ----------------
__global__ void cast4_kernel(const float* __restrict__ in, u16* __restrict__ out, int n4) {
  int i = blockIdx.x * blockDim.x + threadIdx.x;
  for (; i < n4; i += gridDim.x * blockDim.x) {
    f32x4 v = ((const f32x4*)in)[i];
    u16x4 o = { f2b(v[0]), f2b(v[1]), f2b(v[2]), f2b(v[3]) };
    ((u16x4*)out)[i] = o;
  }
}

// in: (K,N) fp32 row-major -> out: (N,K) bf16 row-major (B^T for GEMM)
__global__ void tcast_kernel(const float* __restrict__ in, u16* __restrict__ out, int K, int N) {
  int idx = blockIdx.x * blockDim.x + threadIdx.x;
  if (idx < K * N) {
    int k = idx / N, n = idx % N;
    out[n * K + k] = f2b(in[idx]);
  }
}

// Wr (256,768) -> permuted B^T: pcol(w,nt,l15) holds original col n = gate*256 + 32w + 2*l15 + grp,
// nt = gate*2+grp. Wave w then owns gate triples (z,r,h) for h-cols {32w+2*l15+grp}.
__global__ void wrperm_kernel(const float* __restrict__ in, u16* __restrict__ out) {
  int idx = blockIdx.x * blockDim.x + threadIdx.x;
  if (idx < 256 * 768) {
    int k = idx / 768, n = idx % 768;
    int gate = n >> 8, c = n & 255;
    int w = c >> 5, cc = c & 31, l15 = cc >> 1, grp = cc & 1;
    int nt = gate * 2 + grp;
    out[((((w * 6 + nt) << 4) + l15) << 8) + k] = f2b(in[idx]);
  }
}

// biasMod = bi + [br_z, br_r, 0]: fold recurrent bias for z,r into the input-side GEMM
__global__ void biasmod_kernel(const float* __restrict__ bi, const float* __restrict__ br,
                               float* __restrict__ bm) {
  int n = blockIdx.x * blockDim.x + threadIdx.x;
  if (n < 768) bm[n] = bi[n] + (n < 512 ? br[n] : 0.f);
}

// ---------------- GEMM: C = A @ B + bias, A bf16 row-major, Bt = B^T bf16 (N,K) ----------------
// 128x128 tile, BK=32, 4 waves each owning a 64x64 quadrant, mfma_f32_16x16x32_bf16.
// MODE 0: A rows = bm*128+r (dense), relu, C row-major ldc=256 (h1).
// MODE 1: A rows = bm*512 + t0 + r (T-chunk of batch bm), no relu,
//         C rows = bm*128 + r, natural chunk layout (b, tl, n), ldc=768 (xg chunk).
template<int KT, int MODE>
__global__ __launch_bounds__(256) void gemm_bf16(const u16* __restrict__ A, const u16* __restrict__ Bt,
                                                 const float* __restrict__ bias, u16* __restrict__ C,
                                                 int t0) {
  constexpr int K = KT * 32;
  __shared__ u16 As[128 * 40];  // pad 32->40 shorts/row: conflict-free b128 frag reads
  __shared__ u16 Bs[128 * 40];
  const int tid = threadIdx.x;
  const int bm = blockIdx.x, bn = blockIdx.y;
  const int lane = tid & 63, wid = tid >> 6;
  const int l15 = lane & 15, l4 = lane >> 4;
  const int qm = (wid >> 1) * 64, qn = (wid & 1) * 64;

  const int c0 = tid, c1 = tid + 256;  // 16B chunks: chunk c covers LDS row c/4, k-elems (c%4)*8..+8
  const int ar0 = (MODE == 0) ? (bm * 128 + (c0 >> 2)) : (bm * 512 + t0 + (c0 >> 2));
  const int ar1 = (MODE == 0) ? (bm * 128 + (c1 >> 2)) : (bm * 512 + t0 + (c1 >> 2));
  const size_t ga0 = (size_t)ar0 * K + (c0 & 3) * 8;
  const size_t ga1 = (size_t)ar1 * K + (c1 & 3) * 8;
  const size_t gb0 = (size_t)(bn * 128 + (c0 >> 2)) * K + (c0 & 3) * 8;
  const size_t gb1 = (size_t)(bn * 128 + (c1 >> 2)) * K + (c1 & 3) * 8;
  const int sa0 = (c0 >> 2) * 40 + (c0 & 3) * 8;
  const int sa1 = (c1 >> 2) * 40 + (c1 & 3) * 8;

  uint4 ra0 = *(const uint4*)(A + ga0);
  uint4 ra1 = *(const uint4*)(A + ga1);
  uint4 rb0 = *(const uint4*)(Bt + gb0);
  uint4 rb1 = *(const uint4*)(Bt + gb1);

  f32x4 acc[4][4] = {};

  for (int kt = 0; kt < KT; ++kt) {
    __syncthreads();
    *(uint4*)(As + sa0) = ra0;
    *(uint4*)(As + sa1) = ra1;
    *(uint4*)(Bs + sa0) = rb0;
    *(uint4*)(Bs + sa1) = rb1;
    __syncthreads();
    if (kt + 1 < KT) {  // prefetch next tile into regs under the MFMA phase
      const int ko = (kt + 1) * 32;
      ra0 = *(const uint4*)(A + ga0 + ko);
      ra1 = *(const uint4*)(A + ga1 + ko);
      rb0 = *(const uint4*)(Bt + gb0 + ko);
      rb1 = *(const uint4*)(Bt + gb1 + ko);
    }
    bf16x8 af[4], bfr[4];
#pragma unroll
    for (int mt = 0; mt < 4; ++mt)
      af[mt] = *(const bf16x8*)(As + (qm + mt * 16 + l15) * 40 + l4 * 8);
#pragma unroll
    for (int nt = 0; nt < 4; ++nt)
      bfr[nt] = *(const bf16x8*)(Bs + (qn + nt * 16 + l15) * 40 + l4 * 8);
#pragma unroll
    for (int mt = 0; mt < 4; ++mt)
#pragma unroll
      for (int nt = 0; nt < 4; ++nt)
        acc[mt][nt] = __builtin_amdgcn_mfma_f32_16x16x32_bf16(af[mt], bfr[nt], acc[mt][nt], 0, 0, 0);
  }

#pragma unroll
  for (int mt = 0; mt < 4; ++mt) {
#pragma unroll
    for (int nt = 0; nt < 4; ++nt) {
      const int n = bn * 128 + qn + nt * 16 + l15;
      const float bv = bias[n];
#pragma unroll
      for (int j = 0; j < 4; ++j) {
        const int rloc = qm + mt * 16 + l4 * 4 + j;  // D: row=(lane>>4)*4+j, col=lane&15
        float v = acc[mt][nt][j] + bv;
        if (MODE == 0) {
          v = fmaxf(v, 0.f);
          C[(size_t)(bm * 128 + rloc) * 256 + n] = f2b(v);
        } else {
          C[((size_t)bm * 128 + rloc) * 768 + n] = f2b(v);
        }
      }
    }
  }
}

// ---------------- GRU chunk: 16 WGs x 512 threads (8 waves); WG g owns batch rows 16g..16g+15 ---
// Wave wid holds permuted Wr B-fragments for its 32 h-cols x 3 gates (192 regs, VGPR+AGPR).
// Gates computed in-register on the accumulator lanes; bf16 h ping-pongs through LDS;
// one barrier per step; xq staged through an LDS double buffer one step ahead (R10).
// R11 delta (scheduling only, bit-identical math): MFMA chains split into groups {0,2,4}/{1,3,5}
// with the 12 gate ds_reads issued between them (latency under MFMA), gates grp0/grp1 split so
// grp0 VALU can overlap group-B MFMA issue, and the h-pack uses v_cvt_pk_bf16_f32 (RNE,
// bit-identical to f2b packing -- proven by the R4/R5 bisect).
__global__ __launch_bounds__(512, 2) void gru_kernel(const u16* __restrict__ xgc,
                                                     const u16* __restrict__ WrP,
                                                     const float* __restrict__ br,
                                                     float* __restrict__ hstate, int t0) {
  __shared__ u16 hb0[16 * 264];  // h bf16, [row][col], stride 264 (528 B) - ping
  __shared__ u16 hb1[16 * 264];  // pong
  __shared__ u16 xs0[16 * 776];  // xq stage, [row][col 0..767], stride 776 - ping
  __shared__ u16 xs1[16 * 776];  // pong
  const int tid = threadIdx.x, g = blockIdx.x;
  const int lane = tid & 63, wid = tid >> 6;
  const int l15 = lane & 15, l4 = lane >> 4;

  // register-resident Wr fragments: wave wid covers permuted cols [wid*96, wid*96+96)
  bf16x8 bw[8][6];
#pragma unroll
  for (int kk = 0; kk < 8; ++kk)
#pragma unroll
    for (int nt = 0; nt < 6; ++nt)
      bw[kk][nt] = *(const bf16x8*)(WrP + ((((wid * 6 + nt) << 4) + l15) << 8) + kk * 32 + l4 * 8);

  const int cbase = wid * 32 + l15 * 2;  // this lane's h-col pair
  const float brh0 = br[512 + cbase];
  const float brh1 = br[512 + cbase + 1];

  // staging role: thread stages row rs, u16 cols {ksl, ksl+256, ksl+512} (+8 each)
  const int rs = tid >> 5, ksl = (tid & 31) * 8;
  const u16* xg_row = xgc + (size_t)(g * 16 + rs) * TC * 768 + ksl;
  u16* xw0 = xs0 + rs * 776 + ksl;
  u16* xw1 = xs1 + rs * 776 + ksl;

  f32x4 h0v, h1v;  // fp32 master h for rows l4*4+j, cols cbase/cbase+1
  if (t0 == 0) {
    h0v = {0.f, 0.f, 0.f, 0.f};
    h1v = {0.f, 0.f, 0.f, 0.f};
  } else {
#pragma unroll
    for (int j = 0; j < 4; ++j) {
      float2 ld = *(const float2*)(hstate + ((size_t)g * 16 + l4 * 4 + j) * 256 + cbase);
      h0v[j] = ld.x; h1v[j] = ld.y;
    }
  }
#pragma unroll
  for (int j = 0; j < 4; ++j)
    *(u32*)(hb0 + (l4 * 4 + j) * 264 + cbase) = pkbf(h0v[j], h1v[j]);

  {  // pre-stage step 0 into xs0
    const uint4 s0 = *(const uint4*)(xg_row);
    const uint4 s1 = *(const uint4*)(xg_row + 256);
    const uint4 s2 = *(const uint4*)(xg_row + 512);
    *(uint4*)(xw0) = s0;
    *(uint4*)(xw0 + 256) = s1;
    *(uint4*)(xw0 + 512) = s2;
  }
  __syncthreads();

#define GRU_STEP(SRC, DST, XRD, XWR, TL)                                                    \
  {                                                                                         \
    /* issue next step's stage loads (clamped on last step; dead value) */                  \
    const int tn = ((TL) + 1 < TC) ? ((TL) + 1) : (TC - 1);                                 \
    const u16* xq = xg_row + (size_t)tn * 768;                                              \
    const uint4 s0 = *(const uint4*)(xq);                                                   \
    const uint4 s1 = *(const uint4*)(xq + 256);                                             \
    const uint4 s2 = *(const uint4*)(xq + 512);                                             \
    /* MFMA group A: chains for acc 0,2,4 (grp0 cols) */                                    \
    f32x4 a0 = {}, a2 = {}, a4 = {};                                                        \
    _Pragma("unroll")                                                                       \
    for (int kk = 0; kk < 8; ++kk) {                                                        \
      const bf16x8 a = *(const bf16x8*)((SRC) + l15 * 264 + kk * 32 + l4 * 8);              \
      a0 = __builtin_amdgcn_mfma_f32_16x16x32_bf16(a, bw[kk][0], a0, 0, 0, 0);              \
      a2 = __builtin_amdgcn_mfma_f32_16x16x32_bf16(a, bw[kk][2], a2, 0, 0, 0);              \
      a4 = __builtin_amdgcn_mfma_f32_16x16x32_bf16(a, bw[kk][4], a4, 0, 0, 0);              \
    }                                                                                       \
    /* gate-input reads issued here: latency hidden under MFMA group B */                   \
    u32 xz_[4], xr_[4], xh_[4];                                                             \
    _Pragma("unroll")                                                                       \
    for (int j = 0; j < 4; ++j) {                                                           \
      const u16* xr2 = (XRD) + (l4 * 4 + j) * 776 + cbase;                                  \
      xz_[j] = *(const u32*)(xr2);                                                          \
      xr_[j] = *(const u32*)(xr2 + 256);                                                    \
      xh_[j] = *(const u32*)(xr2 + 512);                                                    \
    }                                                                                       \
    /* MFMA group B: chains for acc 1,3,5 (grp1 cols) */                                    \
    f32x4 a1 = {}, a3 = {}, a5 = {};                                                        \
    _Pragma("unroll")                                                                       \
    for (int kk = 0; kk < 8; ++kk) {                                                        \
      const bf16x8 a = *(const bf16x8*)((SRC) + l15 * 264 + kk * 32 + l4 * 8);              \
      a1 = __builtin_amdgcn_mfma_f32_16x16x32_bf16(a, bw[kk][1], a1, 0, 0, 0);              \
      a3 = __builtin_amdgcn_mfma_f32_16x16x32_bf16(a, bw[kk][3], a3, 0, 0, 0);              \
      a5 = __builtin_amdgcn_mfma_f32_16x16x32_bf16(a, bw[kk][5], a5, 0, 0, 0);              \
    }                                                                                       \
    /* stage next step's xq into the other buffer (read next step, after barrier) */        \
    *(uint4*)(XWR) = s0;                                                                    \
    *(uint4*)((XWR) + 256) = s1;                                                            \
    *(uint4*)((XWR) + 512) = s2;                                                            \
    /* gates grp0 (needs group A accs; can overlap group B issue) */                        \
    _Pragma("unroll")                                                                       \
    for (int j = 0; j < 4; ++j) {                                                           \
      const float z0 = sigm(blo(xz_[j]) + a0[j]);                                           \
      const float r0 = sigm(blo(xr_[j]) + a2[j]);                                           \
      const float hh0 = fmaxf(fmaf(r0, a4[j] + brh0, blo(xh_[j])), 0.f);                    \
      h0v[j] = fmaf(z0, h0v[j] - hh0, hh0);                                                 \
    }                                                                                       \
    /* gates grp1 + packed h write */                                                       \
    _Pragma("unroll")                                                                       \
    for (int j = 0; j < 4; ++j) {                                                           \
      const float z1 = sigm(bhi(xz_[j]) + a1[j]);                                           \
      const float r1 = sigm(bhi(xr_[j]) + a3[j]);                                           \
      const float hh1 = fmaxf(fmaf(r1, a5[j] + brh1, bhi(xh_[j])), 0.f);                    \
      h1v[j] = fmaf(z1, h1v[j] - hh1, hh1);                                                 \
      *(u32*)((DST) + (l4 * 4 + j) * 264 + cbase) = pkbf(h0v[j], h1v[j]);                   \
    }                                                                                       \
    __syncthreads();                                                                        \
  }

  for (int tl = 0; tl < TC; tl += 2) {
    GRU_STEP(hb0, hb1, xs0, xw1, tl);      // compute step tl (data in xs0), stage tl+1 -> xs1
    GRU_STEP(hb1, hb0, xs1, xw0, tl + 1);  // compute step tl+1 (xs1), stage tl+2 -> xs0
  }
#undef GRU_STEP

  // persist carried state (lanes own disjoint (row, colpair) slots)
#pragma unroll
  for (int j = 0; j < 4; ++j) {
    float2 st = {h0v[j], h1v[j]};
    *(float2*)(hstate + ((size_t)g * 16 + l4 * 4 + j) * 256 + cbase) = st;
  }
}

// ---------------- output: y = [h,h] @ W2 + b2 = h @ (W2_top + W2_bot) + b2 ----------------
__global__ void out_kernel(const float* __restrict__ h, const float* __restrict__ W2,
                           const float* __restrict__ b2, float* __restrict__ y) {
  const int bb = blockIdx.x, j = threadIdx.x;  // 256 blocks x 128 threads
  const float* hr = h + (size_t)bb * 256;
  float s = b2[j];
  for (int i = 0; i < 256; ++i)
    s = fmaf(hr[i], W2[i * 128 + j] + W2[(i + 256) * 128 + j], s);
  y[(size_t)bb * 128 + j] = s;
}

extern "C" void kernel_launch(void* const* d_in, const int* in_sizes, int n_in,
                              void* d_out, int out_size, void* d_ws, size_t ws_size,
                              hipStream_t stream) {
  const float* x  = (const float*)d_in[0];
  const float* W1 = (const float*)d_in[1];
  const float* b1 = (const float*)d_in[2];
  const float* Wk = (const float*)d_in[3];
  const float* Wr = (const float*)d_in[4];
  const float* bi = (const float*)d_in[5];
  const float* br = (const float*)d_in[6];
  const float* W2 = (const float*)d_in[7];
  const float* b2 = (const float*)d_in[8];
  float* y = (float*)d_out;

  // workspace: 118.6 MB total; x_bf overlays the xg chunk buffer (dead before gemm2 runs)
  const size_t NEED = 67108864ull + 50331648ull + 65536ull + 393216ull + 393216ull + 262144ull + 4096ull;
  if (ws_size < NEED) return;

  char* ws = (char*)d_ws;
  u16* h1    = (u16*)ws;  ws += 67108864;   // (131072,256) bf16
  u16* xgc   = (u16*)ws;  ws += 50331648;   // (256,128,768) bf16 chunk, natural layout; xb overlay
  u16* W1T   = (u16*)ws;  ws += 65536;      // (256,128) bf16
  u16* WkT   = (u16*)ws;  ws += 393216;     // (768,256) bf16
  u16* WrP   = (u16*)ws;  ws += 393216;     // permuted Wr^T (768,256) bf16
  float* hstate = (float*)ws; ws += 262144; // (256,256) f32 carried GRU state
  float* biasM  = (float*)ws;               // 768 f32
  u16* xb    = xgc;                         // (131072,128) bf16 overlay

  cast4_kernel<<<2048, 256, 0, stream>>>(x, xb, 16777216 / 4);
  tcast_kernel<<<128, 256, 0, stream>>>(W1, W1T, 128, 256);
  tcast_kernel<<<768, 256, 0, stream>>>(Wk, WkT, 256, 768);
  wrperm_kernel<<<768, 256, 0, stream>>>(Wr, WrP);
  biasmod_kernel<<<3, 256, 0, stream>>>(bi, br, biasM);
  gemm_bf16<4, 0><<<dim3(1024, 2), 256, 0, stream>>>(xb, W1T, b1, h1, 0);
  for (int c = 0; c < TT / TC; ++c) {
    gemm_bf16<8, 1><<<dim3(256, 6), 256, 0, stream>>>(h1, WkT, biasM, xgc, c * TC);
    gru_kernel<<<16, 512, 0, stream>>>(xgc, WrP, br, hstate, c * TC);
  }
  out_kernel<<<256, 128, 0, stream>>>(hstate, W2, b2, y);
}

// Round 12
// 1016.348 us; speedup vs baseline: 1.9450x; 1.0242x over previous
//
#include <hip/hip_runtime.h>

typedef unsigned short u16;
typedef unsigned int u32;
typedef float f32x4 __attribute__((ext_vector_type(4)));
typedef __bf16 bf16x8 __attribute__((ext_vector_type(8)));
typedef u16 u16x4 __attribute__((ext_vector_type(4)));

// B=256, T=512, FIN=128, H=256, 3H=768
#define TB 256
#define TT 512
#define TC 64   // T-chunk; 2 chunk buffers double-buffer the gemm2->gru pipeline

__device__ __forceinline__ u16 f2b(float f) {
  u32 x = __float_as_uint(f);
  return (u16)((x + 0x7fffu + ((x >> 16) & 1u)) >> 16);
}
__device__ __forceinline__ u32 pkbf(float a, float b) {  // RNE, bit-identical to f2b pair pack
  u32 r;
  asm("v_cvt_pk_bf16_f32 %0, %1, %2" : "=v"(r) : "v"(a), "v"(b));
  return r;
}
__device__ __forceinline__ float blo(u32 u) { return __uint_as_float(u << 16); }
__device__ __forceinline__ float bhi(u32 u) { return __uint_as_float(u & 0xffff0000u); }
__device__ __forceinline__ float sigm(float x) {
  return __builtin_amdgcn_rcpf(1.f + __expf(-x));
}

// ---------------- casts ----------------
__global__ void cast4_kernel(const float* __restrict__ in, u16* __restrict__ out, int n4) {
  int i = blockIdx.x * blockDim.x + threadIdx.x;
  for (; i < n4; i += gridDim.x * blockDim.x) {
    f32x4 v = ((const f32x4*)in)[i];
    u16x4 o = { f2b(v[0]), f2b(v[1]), f2b(v[2]), f2b(v[3]) };
    ((u16x4*)out)[i] = o;
  }
}

// in: (K,N) fp32 row-major -> out: (N,K) bf16 row-major (B^T for GEMM)
__global__ void tcast_kernel(const float* __restrict__ in, u16* __restrict__ out, int K, int N) {
  int idx = blockIdx.x * blockDim.x + threadIdx.x;
  if (idx < K * N) {
    int k = idx / N, n = idx % N;
    out[n * K + k] = f2b(in[idx]);
  }
}

// Wr (256,768) -> permuted B^T: pcol(w,nt,l15) holds original col n = gate*256 + 32w + 2*l15 + grp,
// nt = gate*2+grp. Wave w then owns gate triples (z,r,h) for h-cols {32w+2*l15+grp}.
__global__ void wrperm_kernel(const float* __restrict__ in, u16* __restrict__ out) {
  int idx = blockIdx.x * blockDim.x + threadIdx.x;
  if (idx < 256 * 768) {
    int k = idx / 768, n = idx % 768;
    int gate = n >> 8, c = n & 255;
    int w = c >> 5, cc = c & 31, l15 = cc >> 1, grp = cc & 1;
    int nt = gate * 2 + grp;
    out[((((w * 6 + nt) << 4) + l15) << 8) + k] = f2b(in[idx]);
  }
}

// biasMod = bi + [br_z, br_r, 0]: fold recurrent bias for z,r into the input-side GEMM
__global__ void biasmod_kernel(const float* __restrict__ bi, const float* __restrict__ br,
                               float* __restrict__ bm) {
  int n = blockIdx.x * blockDim.x + threadIdx.x;
  if (n < 768) bm[n] = bi[n] + (n < 512 ? br[n] : 0.f);
}

// ---------------- GEMM: C = A @ B + bias, A bf16 row-major, Bt = B^T bf16 (N,K) ----------------
// 128x128 tile, BK=32, 4 waves each owning a 64x64 quadrant, mfma_f32_16x16x32_bf16.
// MODE 0: A rows = bm*128+r (dense), relu, C row-major ldc=256 (h1).
// MODE 1 (TC=64 tiles): A rows = (2*bm + (r>>6))*512 + t0 + (r&63)  [2 batches x 64 t per tile],
//         C rows = bm*128 + r (natural chunk layout (b, tl, n)), ldc=768 (xg chunk).
template<int KT, int MODE>
__global__ __launch_bounds__(256) void gemm_bf16(const u16* __restrict__ A, const u16* __restrict__ Bt,
                                                 const float* __restrict__ bias, u16* __restrict__ C,
                                                 int t0) {
  constexpr int K = KT * 32;
  __shared__ u16 As[128 * 40];  // pad 32->40 shorts/row: conflict-free b128 frag reads
  __shared__ u16 Bs[128 * 40];
  const int tid = threadIdx.x;
  const int bm = blockIdx.x, bn = blockIdx.y;
  const int lane = tid & 63, wid = tid >> 6;
  const int l15 = lane & 15, l4 = lane >> 4;
  const int qm = (wid >> 1) * 64, qn = (wid & 1) * 64;

  const int c0 = tid, c1 = tid + 256;  // 16B chunks: chunk c covers LDS row c/4, k-elems (c%4)*8..+8
  const int r0 = c0 >> 2, r1 = c1 >> 2;
  const int ar0 = (MODE == 0) ? (bm * 128 + r0) : ((2 * bm + (r0 >> 6)) * 512 + t0 + (r0 & 63));
  const int ar1 = (MODE == 0) ? (bm * 128 + r1) : ((2 * bm + (r1 >> 6)) * 512 + t0 + (r1 & 63));
  const size_t ga0 = (size_t)ar0 * K + (c0 & 3) * 8;
  const size_t ga1 = (size_t)ar1 * K + (c1 & 3) * 8;
  const size_t gb0 = (size_t)(bn * 128 + r0) * K + (c0 & 3) * 8;
  const size_t gb1 = (size_t)(bn * 128 + r1) * K + (c1 & 3) * 8;
  const int sa0 = r0 * 40 + (c0 & 3) * 8;
  const int sa1 = r1 * 40 + (c1 & 3) * 8;

  uint4 ra0 = *(const uint4*)(A + ga0);
  uint4 ra1 = *(const uint4*)(A + ga1);
  uint4 rb0 = *(const uint4*)(Bt + gb0);
  uint4 rb1 = *(const uint4*)(Bt + gb1);

  f32x4 acc[4][4] = {};

  for (int kt = 0; kt < KT; ++kt) {
    __syncthreads();
    *(uint4*)(As + sa0) = ra0;
    *(uint4*)(As + sa1) = ra1;
    *(uint4*)(Bs + sa0) = rb0;
    *(uint4*)(Bs + sa1) = rb1;
    __syncthreads();
    if (kt + 1 < KT) {  // prefetch next tile into regs under the MFMA phase
      const int ko = (kt + 1) * 32;
      ra0 = *(const uint4*)(A + ga0 + ko);
      ra1 = *(const uint4*)(A + ga1 + ko);
      rb0 = *(const uint4*)(Bt + gb0 + ko);
      rb1 = *(const uint4*)(Bt + gb1 + ko);
    }
    bf16x8 af[4], bfr[4];
#pragma unroll
    for (int mt = 0; mt < 4; ++mt)
      af[mt] = *(const bf16x8*)(As + (qm + mt * 16 + l15) * 40 + l4 * 8);
#pragma unroll
    for (int nt = 0; nt < 4; ++nt)
      bfr[nt] = *(const bf16x8*)(Bs + (qn + nt * 16 + l15) * 40 + l4 * 8);
#pragma unroll
    for (int mt = 0; mt < 4; ++mt)
#pragma unroll
      for (int nt = 0; nt < 4; ++nt)
        acc[mt][nt] = __builtin_amdgcn_mfma_f32_16x16x32_bf16(af[mt], bfr[nt], acc[mt][nt], 0, 0, 0);
  }

#pragma unroll
  for (int mt = 0; mt < 4; ++mt) {
#pragma unroll
    for (int nt = 0; nt < 4; ++nt) {
      const int n = bn * 128 + qn + nt * 16 + l15;
      const float bv = bias[n];
#pragma unroll
      for (int j = 0; j < 4; ++j) {
        const int rloc = qm + mt * 16 + l4 * 4 + j;  // D: row=(lane>>4)*4+j, col=lane&15
        float v = acc[mt][nt][j] + bv;
        if (MODE == 0) {
          v = fmaxf(v, 0.f);
          C[(size_t)(bm * 128 + rloc) * 256 + n] = f2b(v);
        } else {
          C[((size_t)bm * 128 + rloc) * 768 + n] = f2b(v);
        }
      }
    }
  }
}

// ---------------- fused GRU(chunk c) + gemm2(chunk c+1) ----------------
// Blocks 0..15: GRU (R11 body, byte-identical math) reading xrd.
// Blocks 16..783: gemm2 128x128 tiles (2 batches x 64 t) writing xwr for the NEXT chunk;
// 256 active threads + 256 barrier-skeleton threads. Launch-boundary provides the
// xwr->next-launch-gru ordering; no intra-launch dependency exists.
__global__ __launch_bounds__(512, 2) void fused_kernel(
    const u16* __restrict__ xrd, u16* __restrict__ xwr,
    const u16* __restrict__ WrP, const float* __restrict__ br,
    float* __restrict__ hstate, const u16* __restrict__ h1A,
    const u16* __restrict__ WkT, const float* __restrict__ biasM,
    int t0, int do_gemm) {
  __shared__ alignas(16) char smem_c[66560];
  const int tid = threadIdx.x;

  if (blockIdx.x < 16) {
    // ---------------- GRU part ----------------
    u16* hb0 = (u16*)smem_c;              // 16*264 u16 (8448 B) - ping
    u16* hb1 = (u16*)(smem_c + 8448);     // pong
    u16* xs0 = (u16*)(smem_c + 16896);    // 16*776 u16 (24832 B) xq stage - ping
    u16* xs1 = (u16*)(smem_c + 41728);    // pong
    const int g = blockIdx.x;
    const int lane = tid & 63, wid = tid >> 6;
    const int l15 = lane & 15, l4 = lane >> 4;

    bf16x8 bw[8][6];
#pragma unroll
    for (int kk = 0; kk < 8; ++kk)
#pragma unroll
      for (int nt = 0; nt < 6; ++nt)
        bw[kk][nt] = *(const bf16x8*)(WrP + ((((wid * 6 + nt) << 4) + l15) << 8) + kk * 32 + l4 * 8);

    const int cbase = wid * 32 + l15 * 2;
    const float brh0 = br[512 + cbase];
    const float brh1 = br[512 + cbase + 1];

    const int rs = tid >> 5, ksl = (tid & 31) * 8;
    const u16* xg_row = xrd + (size_t)(g * 16 + rs) * TC * 768 + ksl;
    u16* xw0 = xs0 + rs * 776 + ksl;
    u16* xw1 = xs1 + rs * 776 + ksl;

    f32x4 h0v, h1v;
    if (t0 == 0) {
      h0v = {0.f, 0.f, 0.f, 0.f};
      h1v = {0.f, 0.f, 0.f, 0.f};
    } else {
#pragma unroll
      for (int j = 0; j < 4; ++j) {
        float2 ld = *(const float2*)(hstate + ((size_t)g * 16 + l4 * 4 + j) * 256 + cbase);
        h0v[j] = ld.x; h1v[j] = ld.y;
      }
    }
#pragma unroll
    for (int j = 0; j < 4; ++j)
      *(u32*)(hb0 + (l4 * 4 + j) * 264 + cbase) = pkbf(h0v[j], h1v[j]);

    {  // pre-stage step 0 into xs0
      const uint4 s0 = *(const uint4*)(xg_row);
      const uint4 s1 = *(const uint4*)(xg_row + 256);
      const uint4 s2 = *(const uint4*)(xg_row + 512);
      *(uint4*)(xw0) = s0;
      *(uint4*)(xw0 + 256) = s1;
      *(uint4*)(xw0 + 512) = s2;
    }
    __syncthreads();

#define GRU_STEP(SRC, DST, XRD, XWR, TL)                                                    \
  {                                                                                         \
    const int tn = ((TL) + 1 < TC) ? ((TL) + 1) : (TC - 1);                                 \
    const u16* xq = xg_row + (size_t)tn * 768;                                              \
    const uint4 s0 = *(const uint4*)(xq);                                                   \
    const uint4 s1 = *(const uint4*)(xq + 256);                                             \
    const uint4 s2 = *(const uint4*)(xq + 512);                                             \
    f32x4 a0 = {}, a2 = {}, a4 = {};                                                        \
    _Pragma("unroll")                                                                       \
    for (int kk = 0; kk < 8; ++kk) {                                                        \
      const bf16x8 a = *(const bf16x8*)((SRC) + l15 * 264 + kk * 32 + l4 * 8);              \
      a0 = __builtin_amdgcn_mfma_f32_16x16x32_bf16(a, bw[kk][0], a0, 0, 0, 0);              \
      a2 = __builtin_amdgcn_mfma_f32_16x16x32_bf16(a, bw[kk][2], a2, 0, 0, 0);              \
      a4 = __builtin_amdgcn_mfma_f32_16x16x32_bf16(a, bw[kk][4], a4, 0, 0, 0);              \
    }                                                                                       \
    u32 xz_[4], xr_[4], xh_[4];                                                             \
    _Pragma("unroll")                                                                       \
    for (int j = 0; j < 4; ++j) {                                                           \
      const u16* xr2 = (XRD) + (l4 * 4 + j) * 776 + cbase;                                  \
      xz_[j] = *(const u32*)(xr2);                                                          \
      xr_[j] = *(const u32*)(xr2 + 256);                                                    \
      xh_[j] = *(const u32*)(xr2 + 512);                                                    \
    }                                                                                       \
    f32x4 a1 = {}, a3 = {}, a5 = {};                                                        \
    _Pragma("unroll")                                                                       \
    for (int kk = 0; kk < 8; ++kk) {                                                        \
      const bf16x8 a = *(const bf16x8*)((SRC) + l15 * 264 + kk * 32 + l4 * 8);              \
      a1 = __builtin_amdgcn_mfma_f32_16x16x32_bf16(a, bw[kk][1], a1, 0, 0, 0);              \
      a3 = __builtin_amdgcn_mfma_f32_16x16x32_bf16(a, bw[kk][3], a3, 0, 0, 0);              \
      a5 = __builtin_amdgcn_mfma_f32_16x16x32_bf16(a, bw[kk][5], a5, 0, 0, 0);              \
    }                                                                                       \
    *(uint4*)(XWR) = s0;                                                                    \
    *(uint4*)((XWR) + 256) = s1;                                                            \
    *(uint4*)((XWR) + 512) = s2;                                                            \
    _Pragma("unroll")                                                                       \
    for (int j = 0; j < 4; ++j) {                                                           \
      const float z0 = sigm(blo(xz_[j]) + a0[j]);                                           \
      const float r0 = sigm(blo(xr_[j]) + a2[j]);                                           \
      const float hh0 = fmaxf(fmaf(r0, a4[j] + brh0, blo(xh_[j])), 0.f);                    \
      h0v[j] = fmaf(z0, h0v[j] - hh0, hh0);                                                 \
    }                                                                                       \
    _Pragma("unroll")                                                                       \
    for (int j = 0; j < 4; ++j) {                                                           \
      const float z1 = sigm(bhi(xz_[j]) + a1[j]);                                           \
      const float r1 = sigm(bhi(xr_[j]) + a3[j]);                                           \
      const float hh1 = fmaxf(fmaf(r1, a5[j] + brh1, bhi(xh_[j])), 0.f);                    \
      h1v[j] = fmaf(z1, h1v[j] - hh1, hh1);                                                 \
      *(u32*)((DST) + (l4 * 4 + j) * 264 + cbase) = pkbf(h0v[j], h1v[j]);                   \
    }                                                                                       \
    __syncthreads();                                                                        \
  }

    for (int tl = 0; tl < TC; tl += 2) {
      GRU_STEP(hb0, hb1, xs0, xw1, tl);
      GRU_STEP(hb1, hb0, xs1, xw0, tl + 1);
    }
#undef GRU_STEP

#pragma unroll
    for (int j = 0; j < 4; ++j) {
      float2 st = {h0v[j], h1v[j]};
      *(float2*)(hstate + ((size_t)g * 16 + l4 * 4 + j) * 256 + cbase) = st;
    }
  } else {
    // ---------------- gemm2 part (next chunk) ----------------
    if (!do_gemm) return;
    u16* As = (u16*)smem_c;             // [128][40]
    u16* Bs = (u16*)(smem_c + 10240);   // [128][40]
    const int bidx = blockIdx.x - 16;
    const int bm = bidx & 127, bn = bidx >> 7;
    const int t0g = t0 + TC;
    const bool act = (tid < 256);
    const int lane = tid & 63, wid = tid >> 6;
    const int l15 = lane & 15, l4 = lane >> 4;
    const int qm = ((wid & 3) >> 1) * 64, qn = (wid & 1) * 64;

    const int c0 = tid & 255, c1 = (tid & 255) + 256;
    const int r0 = c0 >> 2, r1 = c1 >> 2;
    const int ar0 = (2 * bm + (r0 >> 6)) * 512 + t0g + (r0 & 63);
    const int ar1 = (2 * bm + (r1 >> 6)) * 512 + t0g + (r1 & 63);
    const size_t ga0 = (size_t)ar0 * 256 + (c0 & 3) * 8;
    const size_t ga1 = (size_t)ar1 * 256 + (c1 & 3) * 8;
    const size_t gb0 = (size_t)(bn * 128 + r0) * 256 + (c0 & 3) * 8;
    const size_t gb1 = (size_t)(bn * 128 + r1) * 256 + (c1 & 3) * 8;
    const int sa0 = r0 * 40 + (c0 & 3) * 8;
    const int sa1 = r1 * 40 + (c1 & 3) * 8;

    uint4 ra0 = {}, ra1 = {}, rb0 = {}, rb1 = {};
    if (act) {
      ra0 = *(const uint4*)(h1A + ga0);
      ra1 = *(const uint4*)(h1A + ga1);
      rb0 = *(const uint4*)(WkT + gb0);
      rb1 = *(const uint4*)(WkT + gb1);
    }
    f32x4 acc[4][4] = {};

    for (int kt = 0; kt < 8; ++kt) {
      __syncthreads();
      if (act) {
        *(uint4*)(As + sa0) = ra0;
        *(uint4*)(As + sa1) = ra1;
        *(uint4*)(Bs + sa0) = rb0;
        *(uint4*)(Bs + sa1) = rb1;
      }
      __syncthreads();
      if (act) {
        if (kt + 1 < 8) {
          const int ko = (kt + 1) * 32;
          ra0 = *(const uint4*)(h1A + ga0 + ko);
          ra1 = *(const uint4*)(h1A + ga1 + ko);
          rb0 = *(const uint4*)(WkT + gb0 + ko);
          rb1 = *(const uint4*)(WkT + gb1 + ko);
        }
        bf16x8 af[4], bfr[4];
#pragma unroll
        for (int mt = 0; mt < 4; ++mt)
          af[mt] = *(const bf16x8*)(As + (qm + mt * 16 + l15) * 40 + l4 * 8);
#pragma unroll
        for (int nt = 0; nt < 4; ++nt)
          bfr[nt] = *(const bf16x8*)(Bs + (qn + nt * 16 + l15) * 40 + l4 * 8);
#pragma unroll
        for (int mt = 0; mt < 4; ++mt)
#pragma unroll
          for (int nt = 0; nt < 4; ++nt)
            acc[mt][nt] = __builtin_amdgcn_mfma_f32_16x16x32_bf16(af[mt], bfr[nt], acc[mt][nt], 0, 0, 0);
      }
    }

    if (act) {
#pragma unroll
      for (int mt = 0; mt < 4; ++mt)
#pragma unroll
        for (int nt = 0; nt < 4; ++nt) {
          const int n = bn * 128 + qn + nt * 16 + l15;
          const float bv = biasM[n];
#pragma unroll
          for (int j = 0; j < 4; ++j) {
            const int rloc = qm + mt * 16 + l4 * 4 + j;
            xwr[((size_t)bm * 128 + rloc) * 768 + n] = f2b(acc[mt][nt][j] + bv);
          }
        }
    }
  }
}

// ---------------- output: y = [h,h] @ W2 + b2 = h @ (W2_top + W2_bot) + b2 ----------------
__global__ void out_kernel(const float* __restrict__ h, const float* __restrict__ W2,
                           const float* __restrict__ b2, float* __restrict__ y) {
  const int bb = blockIdx.x, j = threadIdx.x;  // 256 blocks x 128 threads
  const float* hr = h + (size_t)bb * 256;
  float s = b2[j];
  for (int i = 0; i < 256; ++i)
    s = fmaf(hr[i], W2[i * 128 + j] + W2[(i + 256) * 128 + j], s);
  y[(size_t)bb * 128 + j] = s;
}

extern "C" void kernel_launch(void* const* d_in, const int* in_sizes, int n_in,
                              void* d_out, int out_size, void* d_ws, size_t ws_size,
                              hipStream_t stream) {
  const float* x  = (const float*)d_in[0];
  const float* W1 = (const float*)d_in[1];
  const float* b1 = (const float*)d_in[2];
  const float* Wk = (const float*)d_in[3];
  const float* Wr = (const float*)d_in[4];
  const float* bi = (const float*)d_in[5];
  const float* br = (const float*)d_in[6];
  const float* W2 = (const float*)d_in[7];
  const float* b2 = (const float*)d_in[8];
  float* y = (float*)d_out;

  // workspace: 118.6 MB total (identical to R9-R11); xb overlays the xg buffers
  const size_t NEED = 67108864ull + 25165824ull + 25165824ull + 65536ull + 393216ull +
                      393216ull + 262144ull + 4096ull;
  if (ws_size < NEED) return;

  char* ws = (char*)d_ws;
  u16* h1    = (u16*)ws;  ws += 67108864;   // (131072,256) bf16
  u16* xg0   = (u16*)ws;  ws += 25165824;   // (256,64,768) bf16 chunk buffer 0
  u16* xg1   = (u16*)ws;  ws += 25165824;   // chunk buffer 1
  u16* W1T   = (u16*)ws;  ws += 65536;      // (256,128) bf16
  u16* WkT   = (u16*)ws;  ws += 393216;     // (768,256) bf16
  u16* WrP   = (u16*)ws;  ws += 393216;     // permuted Wr^T (768,256) bf16
  float* hstate = (float*)ws; ws += 262144; // (256,256) f32 carried GRU state
  float* biasM  = (float*)ws;               // 768 f32
  u16* xb    = xg0;                         // (131072,128) bf16 overlay (dead before gemm2 c0)

  cast4_kernel<<<2048, 256, 0, stream>>>(x, xb, 16777216 / 4);
  tcast_kernel<<<128, 256, 0, stream>>>(W1, W1T, 128, 256);
  tcast_kernel<<<768, 256, 0, stream>>>(Wk, WkT, 256, 768);
  wrperm_kernel<<<768, 256, 0, stream>>>(Wr, WrP);
  biasmod_kernel<<<3, 256, 0, stream>>>(bi, br, biasM);
  gemm_bf16<4, 0><<<dim3(1024, 2), 256, 0, stream>>>(xb, W1T, b1, h1, 0);
  gemm_bf16<8, 1><<<dim3(128, 6), 256, 0, stream>>>(h1, WkT, biasM, xg0, 0);  // chunk 0
  for (int c = 0; c < TT / TC; ++c) {
    const u16* xrd = (c & 1) ? xg1 : xg0;
    u16* xwr = (c & 1) ? xg0 : xg1;
    fused_kernel<<<784, 512, 0, stream>>>(xrd, xwr, WrP, br, hstate, h1, WkT, biasM,
                                          c * TC, (c < TT / TC - 1) ? 1 : 0);
  }
  out_kernel<<<256, 128, 0, stream>>>(hstate, W2, b2, y);
}

// Round 13
// 1007.552 us; speedup vs baseline: 1.9620x; 1.0087x over previous
//
#include <hip/hip_runtime.h>

typedef unsigned short u16;
typedef unsigned int u32;
typedef float f32x4 __attribute__((ext_vector_type(4)));
typedef __bf16 bf16x8 __attribute__((ext_vector_type(8)));
typedef u16 u16x4 __attribute__((ext_vector_type(4)));

// B=256, T=512, FIN=128, H=256, 3H=768
#define TB 256
#define TT 512
#define TC 64   // T-chunk; 2 chunk buffers double-buffer the gemm2->gru pipeline

__device__ __forceinline__ u16 f2b(float f) {
  u32 x = __float_as_uint(f);
  return (u16)((x + 0x7fffu + ((x >> 16) & 1u)) >> 16);
}
__device__ __forceinline__ u32 pkbf(float a, float b) {  // RNE, bit-identical to f2b pair pack
  u32 r;
  asm("v_cvt_pk_bf16_f32 %0, %1, %2" : "=v"(r) : "v"(a), "v"(b));
  return r;
}
__device__ __forceinline__ float blo(u32 u) { return __uint_as_float(u << 16); }
__device__ __forceinline__ float bhi(u32 u) { return __uint_as_float(u & 0xffff0000u); }
__device__ __forceinline__ float sigm(float x) {
  return __builtin_amdgcn_rcpf(1.f + __expf(-x));
}

// in: (K,N) fp32 row-major -> out: (N,K) bf16 row-major (B^T for GEMM)
__global__ void tcast_kernel(const float* __restrict__ in, u16* __restrict__ out, int K, int N) {
  int idx = blockIdx.x * blockDim.x + threadIdx.x;
  if (idx < K * N) {
    int k = idx / N, n = idx % N;
    out[n * K + k] = f2b(in[idx]);
  }
}

// Wr (256,768) -> permuted B^T: pcol(w,nt,l15) holds original col n = gate*256 + 32w + 2*l15 + grp,
// nt = gate*2+grp. Wave w then owns gate triples (z,r,h) for h-cols {32w+2*l15+grp}.
__global__ void wrperm_kernel(const float* __restrict__ in, u16* __restrict__ out) {
  int idx = blockIdx.x * blockDim.x + threadIdx.x;
  if (idx < 256 * 768) {
    int k = idx / 768, n = idx % 768;
    int gate = n >> 8, c = n & 255;
    int w = c >> 5, cc = c & 31, l15 = cc >> 1, grp = cc & 1;
    int nt = gate * 2 + grp;
    out[((((w * 6 + nt) << 4) + l15) << 8) + k] = f2b(in[idx]);
  }
}

// biasMod = bi + [br_z, br_r, 0]: fold recurrent bias for z,r into the input-side GEMM
__global__ void biasmod_kernel(const float* __restrict__ bi, const float* __restrict__ br,
                               float* __restrict__ bm) {
  int n = blockIdx.x * blockDim.x + threadIdx.x;
  if (n < 768) bm[n] = bi[n] + (n < 512 ? br[n] : 0.f);
}

// ---------------- GEMM: C = A @ B + bias, Bt = B^T bf16 (N,K) ----------------
// 128x128 tile, BK=32, 4 waves each owning a 64x64 quadrant, mfma_f32_16x16x32_bf16.
// CASTA=1: A is fp32; converted to bf16 in-register during staging (pkbf = RNE, bit-identical
//          to the old cast4 path). CASTA=0: A already bf16.
// MODE 0: A rows = bm*128+r (dense), relu, C row-major ldc=256 (h1).
// MODE 1 (TC=64 tiles): A rows = (2*bm + (r>>6))*512 + t0 + (r&63),
//         C rows = bm*128 + r (natural chunk layout (b, tl, n)), ldc=768 (xg chunk).
template<int KT, int MODE, int CASTA>
__global__ __launch_bounds__(256) void gemm_bf16(const void* __restrict__ Av, const u16* __restrict__ Bt,
                                                 const float* __restrict__ bias, u16* __restrict__ C,
                                                 int t0) {
  constexpr int K = KT * 32;
  const u16* A = (const u16*)Av;
  const float* Af = (const float*)Av;
  __shared__ u16 As[128 * 40];  // pad 32->40 shorts/row: conflict-free b128 frag reads
  __shared__ u16 Bs[128 * 40];
  const int tid = threadIdx.x;
  const int bm = blockIdx.x, bn = blockIdx.y;
  const int lane = tid & 63, wid = tid >> 6;
  const int l15 = lane & 15, l4 = lane >> 4;
  const int qm = (wid >> 1) * 64, qn = (wid & 1) * 64;

  const int c0 = tid, c1 = tid + 256;  // 16B chunks: chunk c covers LDS row c/4, k-elems (c%4)*8..+8
  const int r0 = c0 >> 2, r1 = c1 >> 2;
  const int ar0 = (MODE == 0) ? (bm * 128 + r0) : ((2 * bm + (r0 >> 6)) * 512 + t0 + (r0 & 63));
  const int ar1 = (MODE == 0) ? (bm * 128 + r1) : ((2 * bm + (r1 >> 6)) * 512 + t0 + (r1 & 63));
  const size_t ga0 = (size_t)ar0 * K + (c0 & 3) * 8;
  const size_t ga1 = (size_t)ar1 * K + (c1 & 3) * 8;
  const size_t gb0 = (size_t)(bn * 128 + r0) * K + (c0 & 3) * 8;
  const size_t gb1 = (size_t)(bn * 128 + r1) * K + (c1 & 3) * 8;
  const int sa0 = r0 * 40 + (c0 & 3) * 8;
  const int sa1 = r1 * 40 + (c1 & 3) * 8;

#define LOADA(ga, ko, dst)                                                       \
  if (CASTA) {                                                                   \
    const float* p = Af + (ga) + (ko);                                           \
    const f32x4 v0 = *(const f32x4*)(p);                                         \
    const f32x4 v1 = *(const f32x4*)(p + 4);                                     \
    (dst).x = pkbf(v0[0], v0[1]); (dst).y = pkbf(v0[2], v0[3]);                  \
    (dst).z = pkbf(v1[0], v1[1]); (dst).w = pkbf(v1[2], v1[3]);                  \
  } else {                                                                       \
    (dst) = *(const uint4*)(A + (ga) + (ko));                                    \
  }

  uint4 ra0, ra1, rb0, rb1;
  LOADA(ga0, 0, ra0);
  LOADA(ga1, 0, ra1);
  rb0 = *(const uint4*)(Bt + gb0);
  rb1 = *(const uint4*)(Bt + gb1);

  f32x4 acc[4][4] = {};

  for (int kt = 0; kt < KT; ++kt) {
    __syncthreads();
    *(uint4*)(As + sa0) = ra0;
    *(uint4*)(As + sa1) = ra1;
    *(uint4*)(Bs + sa0) = rb0;
    *(uint4*)(Bs + sa1) = rb1;
    __syncthreads();
    if (kt + 1 < KT) {  // prefetch next tile into regs under the MFMA phase
      const int ko = (kt + 1) * 32;
      LOADA(ga0, ko, ra0);
      LOADA(ga1, ko, ra1);
      rb0 = *(const uint4*)(Bt + gb0 + ko);
      rb1 = *(const uint4*)(Bt + gb1 + ko);
    }
    bf16x8 af[4], bfr[4];
#pragma unroll
    for (int mt = 0; mt < 4; ++mt)
      af[mt] = *(const bf16x8*)(As + (qm + mt * 16 + l15) * 40 + l4 * 8);
#pragma unroll
    for (int nt = 0; nt < 4; ++nt)
      bfr[nt] = *(const bf16x8*)(Bs + (qn + nt * 16 + l15) * 40 + l4 * 8);
#pragma unroll
    for (int mt = 0; mt < 4; ++mt)
#pragma unroll
      for (int nt = 0; nt < 4; ++nt)
        acc[mt][nt] = __builtin_amdgcn_mfma_f32_16x16x32_bf16(af[mt], bfr[nt], acc[mt][nt], 0, 0, 0);
  }
#undef LOADA

#pragma unroll
  for (int mt = 0; mt < 4; ++mt) {
#pragma unroll
    for (int nt = 0; nt < 4; ++nt) {
      const int n = bn * 128 + qn + nt * 16 + l15;
      const float bv = bias[n];
#pragma unroll
      for (int j = 0; j < 4; ++j) {
        const int rloc = qm + mt * 16 + l4 * 4 + j;  // D: row=(lane>>4)*4+j, col=lane&15
        float v = acc[mt][nt][j] + bv;
        if (MODE == 0) {
          v = fmaxf(v, 0.f);
          C[(size_t)(bm * 128 + rloc) * 256 + n] = f2b(v);
        } else {
          C[((size_t)bm * 128 + rloc) * 768 + n] = f2b(v);
        }
      }
    }
  }
}

// ---------------- fused GRU(chunk c) + gemm2(chunk c+1) ----------------
// Blocks 0..15: GRU (R11 body, byte-identical math) reading xrd.
// Blocks 16..783: gemm2 128x128 tiles writing xwr for the NEXT chunk.
// smem padded to 82048 B > 160KiB/2 => exactly 1 block/CU: GRU blocks own their CUs
// exclusively (R12's 66560 allowed a gemm block to co-reside and steal MFMA/LDS issue).
__global__ __launch_bounds__(512, 1) void fused_kernel(
    const u16* __restrict__ xrd, u16* __restrict__ xwr,
    const u16* __restrict__ WrP, const float* __restrict__ br,
    float* __restrict__ hstate, const u16* __restrict__ h1A,
    const u16* __restrict__ WkT, const float* __restrict__ biasM,
    int t0, int do_gemm) {
  __shared__ alignas(16) char smem_c[82048];
  const int tid = threadIdx.x;

  if (blockIdx.x < 16) {
    // ---------------- GRU part ----------------
    u16* hb0 = (u16*)smem_c;              // 16*264 u16 (8448 B) - ping
    u16* hb1 = (u16*)(smem_c + 8448);     // pong
    u16* xs0 = (u16*)(smem_c + 16896);    // 16*776 u16 (24832 B) xq stage - ping
    u16* xs1 = (u16*)(smem_c + 41728);    // pong
    const int g = blockIdx.x;
    const int lane = tid & 63, wid = tid >> 6;
    const int l15 = lane & 15, l4 = lane >> 4;

    bf16x8 bw[8][6];
#pragma unroll
    for (int kk = 0; kk < 8; ++kk)
#pragma unroll
      for (int nt = 0; nt < 6; ++nt)
        bw[kk][nt] = *(const bf16x8*)(WrP + ((((wid * 6 + nt) << 4) + l15) << 8) + kk * 32 + l4 * 8);

    const int cbase = wid * 32 + l15 * 2;
    const float brh0 = br[512 + cbase];
    const float brh1 = br[512 + cbase + 1];

    const int rs = tid >> 5, ksl = (tid & 31) * 8;
    const u16* xg_row = xrd + (size_t)(g * 16 + rs) * TC * 768 + ksl;
    u16* xw0 = xs0 + rs * 776 + ksl;
    u16* xw1 = xs1 + rs * 776 + ksl;

    f32x4 h0v, h1v;
    if (t0 == 0) {
      h0v = {0.f, 0.f, 0.f, 0.f};
      h1v = {0.f, 0.f, 0.f, 0.f};
    } else {
#pragma unroll
      for (int j = 0; j < 4; ++j) {
        float2 ld = *(const float2*)(hstate + ((size_t)g * 16 + l4 * 4 + j) * 256 + cbase);
        h0v[j] = ld.x; h1v[j] = ld.y;
      }
    }
#pragma unroll
    for (int j = 0; j < 4; ++j)
      *(u32*)(hb0 + (l4 * 4 + j) * 264 + cbase) = pkbf(h0v[j], h1v[j]);

    {  // pre-stage step 0 into xs0
      const uint4 s0 = *(const uint4*)(xg_row);
      const uint4 s1 = *(const uint4*)(xg_row + 256);
      const uint4 s2 = *(const uint4*)(xg_row + 512);
      *(uint4*)(xw0) = s0;
      *(uint4*)(xw0 + 256) = s1;
      *(uint4*)(xw0 + 512) = s2;
    }
    __syncthreads();

#define GRU_STEP(SRC, DST, XRD, XWR, TL)                                                    \
  {                                                                                         \
    const int tn = ((TL) + 1 < TC) ? ((TL) + 1) : (TC - 1);                                 \
    const u16* xq = xg_row + (size_t)tn * 768;                                              \
    const uint4 s0 = *(const uint4*)(xq);                                                   \
    const uint4 s1 = *(const uint4*)(xq + 256);                                             \
    const uint4 s2 = *(const uint4*)(xq + 512);                                             \
    f32x4 a0 = {}, a2 = {}, a4 = {};                                                        \
    _Pragma("unroll")                                                                       \
    for (int kk = 0; kk < 8; ++kk) {                                                        \
      const bf16x8 a = *(const bf16x8*)((SRC) + l15 * 264 + kk * 32 + l4 * 8);              \
      a0 = __builtin_amdgcn_mfma_f32_16x16x32_bf16(a, bw[kk][0], a0, 0, 0, 0);              \
      a2 = __builtin_amdgcn_mfma_f32_16x16x32_bf16(a, bw[kk][2], a2, 0, 0, 0);              \
      a4 = __builtin_amdgcn_mfma_f32_16x16x32_bf16(a, bw[kk][4], a4, 0, 0, 0);              \
    }                                                                                       \
    u32 xz_[4], xr_[4], xh_[4];                                                             \
    _Pragma("unroll")                                                                       \
    for (int j = 0; j < 4; ++j) {                                                           \
      const u16* xr2 = (XRD) + (l4 * 4 + j) * 776 + cbase;                                  \
      xz_[j] = *(const u32*)(xr2);                                                          \
      xr_[j] = *(const u32*)(xr2 + 256);                                                    \
      xh_[j] = *(const u32*)(xr2 + 512);                                                    \
    }                                                                                       \
    f32x4 a1 = {}, a3 = {}, a5 = {};                                                        \
    _Pragma("unroll")                                                                       \
    for (int kk = 0; kk < 8; ++kk) {                                                        \
      const bf16x8 a = *(const bf16x8*)((SRC) + l15 * 264 + kk * 32 + l4 * 8);              \
      a1 = __builtin_amdgcn_mfma_f32_16x16x32_bf16(a, bw[kk][1], a1, 0, 0, 0);              \
      a3 = __builtin_amdgcn_mfma_f32_16x16x32_bf16(a, bw[kk][3], a3, 0, 0, 0);              \
      a5 = __builtin_amdgcn_mfma_f32_16x16x32_bf16(a, bw[kk][5], a5, 0, 0, 0);              \
    }                                                                                       \
    *(uint4*)(XWR) = s0;                                                                    \
    *(uint4*)((XWR) + 256) = s1;                                                            \
    *(uint4*)((XWR) + 512) = s2;                                                            \
    _Pragma("unroll")                                                                       \
    for (int j = 0; j < 4; ++j) {                                                           \
      const float z0 = sigm(blo(xz_[j]) + a0[j]);                                           \
      const float r0 = sigm(blo(xr_[j]) + a2[j]);                                           \
      const float hh0 = fmaxf(fmaf(r0, a4[j] + brh0, blo(xh_[j])), 0.f);                    \
      h0v[j] = fmaf(z0, h0v[j] - hh0, hh0);                                                 \
    }                                                                                       \
    _Pragma("unroll")                                                                       \
    for (int j = 0; j < 4; ++j) {                                                           \
      const float z1 = sigm(bhi(xz_[j]) + a1[j]);                                           \
      const float r1 = sigm(bhi(xr_[j]) + a3[j]);                                           \
      const float hh1 = fmaxf(fmaf(r1, a5[j] + brh1, bhi(xh_[j])), 0.f);                    \
      h1v[j] = fmaf(z1, h1v[j] - hh1, hh1);                                                 \
      *(u32*)((DST) + (l4 * 4 + j) * 264 + cbase) = pkbf(h0v[j], h1v[j]);                   \
    }                                                                                       \
    __syncthreads();                                                                        \
  }

    for (int tl = 0; tl < TC; tl += 2) {
      GRU_STEP(hb0, hb1, xs0, xw1, tl);
      GRU_STEP(hb1, hb0, xs1, xw0, tl + 1);
    }
#undef GRU_STEP

#pragma unroll
    for (int j = 0; j < 4; ++j) {
      float2 st = {h0v[j], h1v[j]};
      *(float2*)(hstate + ((size_t)g * 16 + l4 * 4 + j) * 256 + cbase) = st;
    }
  } else {
    // ---------------- gemm2 part (next chunk) ----------------
    if (!do_gemm) return;
    u16* As = (u16*)smem_c;             // [128][40]
    u16* Bs = (u16*)(smem_c + 10240);   // [128][40]
    const int bidx = blockIdx.x - 16;
    const int bm = bidx & 127, bn = bidx >> 7;
    const int t0g = t0 + TC;
    const bool act = (tid < 256);
    const int lane = tid & 63, wid = tid >> 6;
    const int l15 = lane & 15, l4 = lane >> 4;
    const int qm = ((wid & 3) >> 1) * 64, qn = (wid & 1) * 64;

    const int c0 = tid & 255, c1 = (tid & 255) + 256;
    const int r0 = c0 >> 2, r1 = c1 >> 2;
    const int ar0 = (2 * bm + (r0 >> 6)) * 512 + t0g + (r0 & 63);
    const int ar1 = (2 * bm + (r1 >> 6)) * 512 + t0g + (r1 & 63);
    const size_t ga0 = (size_t)ar0 * 256 + (c0 & 3) * 8;
    const size_t ga1 = (size_t)ar1 * 256 + (c1 & 3) * 8;
    const size_t gb0 = (size_t)(bn * 128 + r0) * 256 + (c0 & 3) * 8;
    const size_t gb1 = (size_t)(bn * 128 + r1) * 256 + (c1 & 3) * 8;
    const int sa0 = r0 * 40 + (c0 & 3) * 8;
    const int sa1 = r1 * 40 + (c1 & 3) * 8;

    uint4 ra0 = {}, ra1 = {}, rb0 = {}, rb1 = {};
    if (act) {
      ra0 = *(const uint4*)(h1A + ga0);
      ra1 = *(const uint4*)(h1A + ga1);
      rb0 = *(const uint4*)(WkT + gb0);
      rb1 = *(const uint4*)(WkT + gb1);
    }
    f32x4 acc[4][4] = {};

    for (int kt = 0; kt < 8; ++kt) {
      __syncthreads();
      if (act) {
        *(uint4*)(As + sa0) = ra0;
        *(uint4*)(As + sa1) = ra1;
        *(uint4*)(Bs + sa0) = rb0;
        *(uint4*)(Bs + sa1) = rb1;
      }
      __syncthreads();
      if (act) {
        if (kt + 1 < 8) {
          const int ko = (kt + 1) * 32;
          ra0 = *(const uint4*)(h1A + ga0 + ko);
          ra1 = *(const uint4*)(h1A + ga1 + ko);
          rb0 = *(const uint4*)(WkT + gb0 + ko);
          rb1 = *(const uint4*)(WkT + gb1 + ko);
        }
        bf16x8 af[4], bfr[4];
#pragma unroll
        for (int mt = 0; mt < 4; ++mt)
          af[mt] = *(const bf16x8*)(As + (qm + mt * 16 + l15) * 40 + l4 * 8);
#pragma unroll
        for (int nt = 0; nt < 4; ++nt)
          bfr[nt] = *(const bf16x8*)(Bs + (qn + nt * 16 + l15) * 40 + l4 * 8);
#pragma unroll
        for (int mt = 0; mt < 4; ++mt)
#pragma unroll
          for (int nt = 0; nt < 4; ++nt)
            acc[mt][nt] = __builtin_amdgcn_mfma_f32_16x16x32_bf16(af[mt], bfr[nt], acc[mt][nt], 0, 0, 0);
      }
    }

    if (act) {
#pragma unroll
      for (int mt = 0; mt < 4; ++mt)
#pragma unroll
        for (int nt = 0; nt < 4; ++nt) {
          const int n = bn * 128 + qn + nt * 16 + l15;
          const float bv = biasM[n];
#pragma unroll
          for (int j = 0; j < 4; ++j) {
            const int rloc = qm + mt * 16 + l4 * 4 + j;
            xwr[((size_t)bm * 128 + rloc) * 768 + n] = f2b(acc[mt][nt][j] + bv);
          }
        }
    }
  }
}

// ---------------- output: y = [h,h] @ W2 + b2 = h @ (W2_top + W2_bot) + b2 ----------------
__global__ void out_kernel(const float* __restrict__ h, const float* __restrict__ W2,
                           const float* __restrict__ b2, float* __restrict__ y) {
  const int bb = blockIdx.x, j = threadIdx.x;  // 256 blocks x 128 threads
  const float* hr = h + (size_t)bb * 256;
  float s = b2[j];
  for (int i = 0; i < 256; ++i)
    s = fmaf(hr[i], W2[i * 128 + j] + W2[(i + 256) * 128 + j], s);
  y[(size_t)bb * 128 + j] = s;
}

extern "C" void kernel_launch(void* const* d_in, const int* in_sizes, int n_in,
                              void* d_out, int out_size, void* d_ws, size_t ws_size,
                              hipStream_t stream) {
  const float* x  = (const float*)d_in[0];
  const float* W1 = (const float*)d_in[1];
  const float* b1 = (const float*)d_in[2];
  const float* Wk = (const float*)d_in[3];
  const float* Wr = (const float*)d_in[4];
  const float* bi = (const float*)d_in[5];
  const float* br = (const float*)d_in[6];
  const float* W2 = (const float*)d_in[7];
  const float* b2 = (const float*)d_in[8];
  float* y = (float*)d_out;

  // workspace: 118.6 MB total (identical to R12); cast4/xb overlay eliminated
  const size_t NEED = 67108864ull + 25165824ull + 25165824ull + 65536ull + 393216ull +
                      393216ull + 262144ull + 4096ull;
  if (ws_size < NEED) return;

  char* ws = (char*)d_ws;
  u16* h1    = (u16*)ws;  ws += 67108864;   // (131072,256) bf16
  u16* xg0   = (u16*)ws;  ws += 25165824;   // (256,64,768) bf16 chunk buffer 0
  u16* xg1   = (u16*)ws;  ws += 25165824;   // chunk buffer 1
  u16* W1T   = (u16*)ws;  ws += 65536;      // (256,128) bf16
  u16* WkT   = (u16*)ws;  ws += 393216;     // (768,256) bf16
  u16* WrP   = (u16*)ws;  ws += 393216;     // permuted Wr^T (768,256) bf16
  float* hstate = (float*)ws; ws += 262144; // (256,256) f32 carried GRU state
  float* biasM  = (float*)ws;               // 768 f32

  tcast_kernel<<<128, 256, 0, stream>>>(W1, W1T, 128, 256);
  tcast_kernel<<<768, 256, 0, stream>>>(Wk, WkT, 256, 768);
  wrperm_kernel<<<768, 256, 0, stream>>>(Wr, WrP);
  biasmod_kernel<<<3, 256, 0, stream>>>(bi, br, biasM);
  gemm_bf16<4, 0, 1><<<dim3(1024, 2), 256, 0, stream>>>(x, W1T, b1, h1, 0);   // cast fused
  gemm_bf16<8, 1, 0><<<dim3(128, 6), 256, 0, stream>>>(h1, WkT, biasM, xg0, 0);  // chunk 0
  for (int c = 0; c < TT / TC; ++c) {
    const u16* xrd = (c & 1) ? xg1 : xg0;
    u16* xwr = (c & 1) ? xg0 : xg1;
    fused_kernel<<<784, 512, 0, stream>>>(xrd, xwr, WrP, br, hstate, h1, WkT, biasM,
                                          c * TC, (c < TT / TC - 1) ? 1 : 0);
  }
  out_kernel<<<256, 128, 0, stream>>>(hstate, W2, b2, y);
}